// Round 2
// baseline (4590.274 us; speedup 1.0000x reference)
//
#include <hip/hip_runtime.h>
#include <math.h>

#define NPTS   200000
#define NPAIR  100000
#define CR     64
#define CR2    32

// scale segment counts / offsets
#define NSEG0      1382400
#define CNT_OFF1   1382400
#define CNT_OFF2   1555200
#define CNT_OFF3   1612800
#define CNT_TOTAL  1634400
#define SUM123_ROW2 172800   // s2 row offset inside sum123
#define SUM123_ROW3 230400   // s3 row offset inside sum123
#define SUM123_ROWS 252000   // total rows in sum123 (s1+s2+s3)

#define TVSEG  1382400       // B*GZ2*GY2*GX2 = 2*16*180*240
#define GX2    240
#define GY2    180
#define GZ2    16

__device__ __forceinline__ int lin_scale(int b, int x, int y, int z,
                                         int ps, int dx, int dy, int dz) {
    int qx = x / ps, qy = y / ps, qz = z / ps;
    return ((b * dx + qx) * dy + qy) * dz + qz;
}

// ---------------- K1: reduced = relu(input @ W_red + b_red) ----------------
__global__ __launch_bounds__(256) void k_reduced(
        const float* __restrict__ in, const float* __restrict__ Wred,
        const float* __restrict__ bred, float* __restrict__ red) {
    __shared__ float Wl[CR * CR];
    __shared__ float bl[CR];
    for (int i = threadIdx.x; i < CR * CR; i += blockDim.x) Wl[i] = Wred[i];
    if (threadIdx.x < CR) bl[threadIdx.x] = bred[threadIdx.x];
    __syncthreads();
    int lane = threadIdx.x & 63;
    int wid  = blockIdx.x * (blockDim.x >> 6) + (threadIdx.x >> 6);
    int nw   = gridDim.x * (blockDim.x >> 6);
    for (int r = wid; r < NPTS; r += nw) {
        float x = in[r * CR + lane];
        float acc = bl[lane];
#pragma unroll
        for (int k = 0; k < CR; ++k)
            acc += __shfl(x, k, 64) * Wl[k * CR + lane];
        red[r * CR + lane] = fmaxf(acc, 0.f);
    }
}

// ---------------- K2: scatter-add segment sums + counts ----------------
__global__ __launch_bounds__(256) void k_scatter(
        const float* __restrict__ red, const int* __restrict__ coords,
        float* __restrict__ sum0, float* __restrict__ sum123,
        float* __restrict__ cnt) {
    int lane = threadIdx.x & 63;
    int wid  = blockIdx.x * (blockDim.x >> 6) + (threadIdx.x >> 6);
    int nw   = gridDim.x * (blockDim.x >> 6);
    for (int r = wid; r < NPTS; r += nw) {
        int cb = coords[4 * r + 0], cx = coords[4 * r + 1];
        int cy = coords[4 * r + 2], cz = coords[4 * r + 3];
        int l0 = lin_scale(cb, cx, cy, cz, 2, 240, 180, 16);
        int l1 = lin_scale(cb, cx, cy, cz, 4, 120,  90,  8);
        int l2 = lin_scale(cb, cx, cy, cz, 6,  80,  60,  6);
        int l3 = lin_scale(cb, cx, cy, cz, 8,  60,  45,  4);
        float v = red[r * CR + lane];
        atomicAdd(&sum0[(size_t)l0 * CR + lane], v);
        atomicAdd(&sum123[(size_t)l1 * CR + lane], v);
        atomicAdd(&sum123[(size_t)(SUM123_ROW2 + l2) * CR + lane], v);
        atomicAdd(&sum123[(size_t)(SUM123_ROW3 + l3) * CR + lane], v);
        if (lane < 4) {
            int myLin, myOff;
            if (lane == 0)      { myLin = l0; myOff = 0; }
            else if (lane == 1) { myLin = l1; myOff = CNT_OFF1; }
            else if (lane == 2) { myLin = l2; myOff = CNT_OFF2; }
            else                { myLin = l3; myOff = CNT_OFF3; }
            atomicAdd(&cnt[myOff + myLin], 1.0f);
        }
    }
}

// ---------------- K3a: att for scales 1-3, in place into sum123 rows ----------------
// row s of sum123 (64 floats of segment sums) is replaced (first 32 floats)
// by att[s][0..31] = relu(mean_s @ fc_list_W[j] + fc_list_b[j]).
__global__ __launch_bounds__(256) void k_att123(
        float* __restrict__ sum123, const float* __restrict__ cnt,
        const float* __restrict__ fcW, const float* __restrict__ fcB) {
    __shared__ float sw[3 * CR * CR2];   // fcW scales 1..3, 24 KB
    for (int i = threadIdx.x; i < 3 * CR * CR2; i += blockDim.x)
        sw[i] = fcW[CR * CR2 + i];
    __syncthreads();
    int lane = threadIdx.x & 63;
    int d = lane & 31;
    int h = lane >> 5;
    float b1 = fcB[1 * CR2 + d], b2 = fcB[2 * CR2 + d], b3 = fcB[3 * CR2 + d];
    int wid = blockIdx.x * (blockDim.x >> 6) + (threadIdx.x >> 6);
    int nw  = gridDim.x * (blockDim.x >> 6);
    for (int s = wid; s < SUM123_ROWS; s += nw) {
        const float* w; int ci; float bj;
        if (s < SUM123_ROW2)      { w = sw;                ci = CNT_OFF1 + s;                 bj = b1; }
        else if (s < SUM123_ROW3) { w = sw + CR * CR2;     ci = CNT_OFF2 + (s - SUM123_ROW2); bj = b2; }
        else                      { w = sw + 2 * CR * CR2; ci = CNT_OFF3 + (s - SUM123_ROW3); bj = b3; }
        float* row = sum123 + (size_t)s * CR;
        float rc = 1.f / fmaxf(cnt[ci], 1.f);
        float m = row[lane] * rc;
        float p = 0.f;
#pragma unroll
        for (int kk = 0; kk < 32; ++kk)
            p += __shfl(m, 32 * h + kk, 64) * w[(32 * h + kk) * CR2 + d];
        float att = fmaxf(p + __shfl_xor(p, 32, 64) + bj, 0.f);
        if (h == 0) row[d] = att;   // in-place, after read
    }
}

// ---------------- K3b: fused per-point chain -> proj0 ----------------
// All weights in LDS; 2 points per wave iteration (shared weight reads, 2x ILP).
__global__ __launch_bounds__(1024) void k_point(
        const float* __restrict__ red,
        const float* __restrict__ sum0, const float* __restrict__ sum123,
        const float* __restrict__ cnt, const int* __restrict__ coords,
        const float* __restrict__ fcW, const float* __restrict__ fcB,
        const float* __restrict__ fcsW, const float* __restrict__ fcsB,
        const float* __restrict__ fc_W, const float* __restrict__ outW,
        const float* __restrict__ loW1, const float* __restrict__ loW2,
        const float* __restrict__ lob2, float* __restrict__ proj0) {
    __shared__ float sw[21504];          // 86 KB
    float* s_fcW0 = sw;                  // 2048: fc_list_W[0] (64x32)
    float* s_fcZ  = sw + 2048;           // 1024: fc_W (32x32)
    float* s_fcs  = sw + 3072;           // 4096: fcsW (4x32x32)
    float* s_out  = sw + 7168;           // 2048: out_fc_W (32x64)
    float* s_W1   = sw + 9216;           // 8192: lo_W1 (128x64)
    float* s_W2   = sw + 17408;          // 4096: lo_W2 (64x64)
    for (int i = threadIdx.x; i < 2048; i += blockDim.x) s_fcW0[i] = fcW[i];
    for (int i = threadIdx.x; i < 1024; i += blockDim.x) s_fcZ[i]  = fc_W[i];
    for (int i = threadIdx.x; i < 4096; i += blockDim.x) s_fcs[i]  = fcsW[i];
    for (int i = threadIdx.x; i < 2048; i += blockDim.x) s_out[i]  = outW[i];
    for (int i = threadIdx.x; i < 8192; i += blockDim.x) s_W1[i]   = loW1[i];
    for (int i = threadIdx.x; i < 4096; i += blockDim.x) s_W2[i]   = loW2[i];
    __syncthreads();

    int lane = threadIdx.x & 63;
    int d = lane & 31;
    int h = lane >> 5;
    float bias0 = fcB[d];                       // scale-0 bias
    float vbA = fcsB[(h ? 1 : 0) * CR2 + d];
    float vbB = fcsB[(h ? 3 : 2) * CR2 + d];
    float lob = lob2[lane];
    const float* VA = s_fcs + (h ? 1 : 0) * CR2 * CR2;
    const float* VB = s_fcs + (h ? 3 : 2) * CR2 * CR2;

    int wid = blockIdx.x * (blockDim.x >> 6) + (threadIdx.x >> 6);
    int nw  = gridDim.x * (blockDim.x >> 6);
    for (int pi = wid; pi < NPAIR; pi += nw) {
        int r0 = 2 * pi, r1 = r0 + 1;
        int4 c0 = ((const int4*)coords)[r0];
        int4 c1 = ((const int4*)coords)[r1];
        int l0a = lin_scale(c0.x, c0.y, c0.z, c0.w, 2, 240, 180, 16);
        int l1a = lin_scale(c0.x, c0.y, c0.z, c0.w, 4, 120,  90,  8);
        int l2a = lin_scale(c0.x, c0.y, c0.z, c0.w, 6,  80,  60,  6);
        int l3a = lin_scale(c0.x, c0.y, c0.z, c0.w, 8,  60,  45,  4);
        int l0b = lin_scale(c1.x, c1.y, c1.z, c1.w, 2, 240, 180, 16);
        int l1b = lin_scale(c1.x, c1.y, c1.z, c1.w, 4, 120,  90,  8);
        int l2b = lin_scale(c1.x, c1.y, c1.z, c1.w, 6,  80,  60,  6);
        int l3b = lin_scale(c1.x, c1.y, c1.z, c1.w, 8,  60,  45,  4);

        float xr0 = red[(size_t)r0 * CR + lane];
        float xr1 = red[(size_t)r1 * CR + lane];
        float rc0 = 1.f / fmaxf(cnt[l0a], 1.f);
        float rc1 = 1.f / fmaxf(cnt[l0b], 1.f);
        float m0 = sum0[(size_t)l0a * CR + lane] * rc0;
        float m1 = sum0[(size_t)l0b * CR + lane] * rc1;
        // gather materialized att (scales 1-3), replicated across halves
        float a1_0 = sum123[(size_t)l1a * CR + d];
        float a2_0 = sum123[(size_t)(SUM123_ROW2 + l2a) * CR + d];
        float a3_0 = sum123[(size_t)(SUM123_ROW3 + l3a) * CR + d];
        float a1_1 = sum123[(size_t)l1b * CR + d];
        float a2_1 = sum123[(size_t)(SUM123_ROW2 + l2b) * CR + d];
        float a3_1 = sum123[(size_t)(SUM123_ROW3 + l3b) * CR + d];

        // scale-0 att: half-wave K-split
        float p0 = 0.f, p1 = 0.f;
#pragma unroll
        for (int kk = 0; kk < 32; ++kk) {
            float w = s_fcW0[(32 * h + kk) * CR2 + d];
            p0 += __shfl(m0, 32 * h + kk, 64) * w;
            p1 += __shfl(m1, 32 * h + kk, 64) * w;
        }
        float sf0_0 = fmaxf(p0 + __shfl_xor(p0, 32, 64) + bias0, 0.f);
        float sf0_1 = fmaxf(p1 + __shfl_xor(p1, 32, 64) + bias0, 0.f);

        float fS0 = sf0_0 + a1_0 + a2_0 + a3_0;   // replicated
        float fS1 = sf0_1 + a1_1 + a2_1 + a3_1;

        // featZ = relu(featS @ fc_W)
        float az0 = 0.f, az1 = 0.f;
#pragma unroll
        for (int c = 0; c < CR2; ++c) {
            float w = s_fcZ[c * CR2 + d];
            az0 += __shfl(fS0, c, 64) * w;
            az1 += __shfl(fS1, c, 64) * w;
        }
        float fZ0 = fmaxf(az0, 0.f), fZ1 = fmaxf(az1, 0.f);

        // att_v (sigmoid); half h handles scales {h, 2+h}
        float avA0 = vbA, avB0 = vbB, avA1 = vbA, avB1 = vbB;
#pragma unroll
        for (int c = 0; c < CR2; ++c) {
            float wa = VA[c * CR2 + d];
            float wb = VB[c * CR2 + d];
            float fz0 = __shfl(fZ0, c, 64);
            float fz1 = __shfl(fZ1, c, 64);
            avA0 += fz0 * wa; avB0 += fz0 * wb;
            avA1 += fz1 * wa; avB1 += fz1 * wb;
        }
        avA0 = 1.f / (1.f + __expf(-avA0));
        avB0 = 1.f / (1.f + __expf(-avB0));
        avA1 = 1.f / (1.f + __expf(-avA1));
        avB1 = 1.f / (1.f + __expf(-avB1));

        float sA0 = h ? a1_0 : sf0_0, sB0 = h ? a3_0 : a2_0;
        float sA1 = h ? a1_1 : sf0_1, sB1 = h ? a3_1 : a2_1;
        float u0 = sA0 * avA0 + sB0 * avB0;
        float u1 = sA1 * avA1 + sB1 * avB1;
        float fI0 = u0 + __shfl_xor(u0, 32, 64);
        float fI1 = u1 + __shfl_xor(u1, 32, 64);

        // fused = fusedIn @ out_fc_W
        float fu0 = 0.f, fu1 = 0.f;
#pragma unroll
        for (int dd = 0; dd < CR2; ++dd) {
            float w = s_out[dd * CR + lane];
            fu0 += __shfl(fI0, dd, 64) * w;
            fu1 += __shfl(fI1, dd, 64) * w;
        }

        // h = relu([reduced, fused] @ lo_W1)
        float h0 = 0.f, h1 = 0.f;
#pragma unroll
        for (int k = 0; k < CR; ++k) {
            float w = s_W1[k * CR + lane];
            h0 += __shfl(xr0, k, 64) * w;
            h1 += __shfl(xr1, k, 64) * w;
        }
#pragma unroll
        for (int k = 0; k < CR; ++k) {
            float w = s_W1[(CR + k) * CR + lane];
            h0 += __shfl(fu0, k, 64) * w;
            h1 += __shfl(fu1, k, 64) * w;
        }
        h0 = fmaxf(h0, 0.f); h1 = fmaxf(h1, 0.f);

        // proj = h @ lo_W2 + lo_b2
        float q0 = lob, q1 = lob;
#pragma unroll
        for (int k = 0; k < CR; ++k) {
            float w = s_W2[k * CR + lane];
            q0 += __shfl(h0, k, 64) * w;
            q1 += __shfl(h1, k, 64) * w;
        }
        proj0[(size_t)r0 * CR + lane] = q0;
        proj0[(size_t)r1 * CR + lane] = q1;
    }
}

// orderable-uint encoding for float max
__device__ __forceinline__ unsigned int fkey(float f) {
    unsigned int b = __float_as_uint(f);
    return (b & 0x80000000u) ? ~b : (b | 0x80000000u);
}

// ---------------- K4: gather proj, write lin2, scatter tv keys ----------------
__global__ __launch_bounds__(256) void k_gather(
        const float* __restrict__ proj0, const int* __restrict__ inv,
        const int* __restrict__ bxyz, float* __restrict__ outProj,
        float* __restrict__ outLin, unsigned int* __restrict__ tvKey) {
    int lane = threadIdx.x & 63;
    int wid  = blockIdx.x * (blockDim.x >> 6) + (threadIdx.x >> 6);
    int nw   = gridDim.x * (blockDim.x >> 6);
    for (int i = wid; i < NPTS; i += nw) {
        int src = inv[i];
        float v = proj0[(size_t)src * CR + lane];
        outProj[(size_t)i * CR + lane] = v;
        int b = bxyz[4 * i + 0], x = bxyz[4 * i + 1];
        int y = bxyz[4 * i + 2], z = bxyz[4 * i + 3];
        int lin2 = ((b * GZ2 + z) * GY2 + y) * GX2 + x;
        if (lane == 0) outLin[i] = (float)lin2;
        atomicMax(&tvKey[(size_t)lin2 * CR + lane], fkey(v));
    }
}

// ---------------- K5: decode tv keys in place (empty -> 0) ----------------
__global__ __launch_bounds__(256) void k_fix(unsigned int* __restrict__ tv) {
    size_t i = ((size_t)blockIdx.x * blockDim.x + threadIdx.x) * 4;
    if (i >= (size_t)TVSEG * CR) return;
    uint4 k = *(const uint4*)(tv + i);
    float4 f;
    f.x = (k.x == 0u) ? 0.f : __uint_as_float((k.x & 0x80000000u) ? (k.x & 0x7FFFFFFFu) : ~k.x);
    f.y = (k.y == 0u) ? 0.f : __uint_as_float((k.y & 0x80000000u) ? (k.y & 0x7FFFFFFFu) : ~k.y);
    f.z = (k.z == 0u) ? 0.f : __uint_as_float((k.z & 0x80000000u) ? (k.z & 0x7FFFFFFFu) : ~k.z);
    f.w = (k.w == 0u) ? 0.f : __uint_as_float((k.w & 0x80000000u) ? (k.w & 0x7FFFFFFFu) : ~k.w);
    *(float4*)(tv + i) = f;
}

extern "C" void kernel_launch(void* const* d_in, const int* in_sizes, int n_in,
                              void* d_out, int out_size, void* d_ws, size_t ws_size,
                              hipStream_t stream) {
    (void)in_sizes; (void)n_in; (void)out_size; (void)ws_size;
    const float* in_data = (const float*)d_in[0];
    const int*   coords  = (const int*)d_in[1];
    const int*   inv     = (const int*)d_in[2];
    const int*   bxyz    = (const int*)d_in[3];
    const float* W_red   = (const float*)d_in[4];
    const float* b_red   = (const float*)d_in[5];
    const float* fcW     = (const float*)d_in[6];
    const float* fcB     = (const float*)d_in[7];
    const float* fcsW    = (const float*)d_in[8];
    const float* fcsB    = (const float*)d_in[9];
    const float* fc_W    = (const float*)d_in[10];
    const float* outW    = (const float*)d_in[11];
    const float* loW1    = (const float*)d_in[12];
    const float* loW2    = (const float*)d_in[13];
    const float* lob2    = (const float*)d_in[14];

    float* outProj = (float*)d_out;
    float* tv      = outProj + (size_t)NPTS * CR;        // tv_fmap region (also scale-0 sum scratch)
    float* outLin  = tv + (size_t)TVSEG * CR;

    float* ws_f   = (float*)d_ws;
    float* red    = ws_f;                                // N*64
    float* sum123 = red + (size_t)NPTS * CR;             // 252000*64 (sums, then att in-place)
    float* cnt    = sum123 + (size_t)SUM123_ROWS * CR;   // 1,634,400
    float* proj0  = cnt + (size_t)CNT_TOTAL;             // N*64

    // zero scale-0 sums (in d_out tv region) and ws sums/counts
    hipMemsetAsync(tv, 0, (size_t)TVSEG * CR * sizeof(float), stream);
    hipMemsetAsync(sum123, 0, ((size_t)SUM123_ROWS * CR + CNT_TOTAL) * sizeof(float), stream);

    k_reduced<<<2048, 256, 0, stream>>>(in_data, W_red, b_red, red);
    k_scatter<<<4096, 256, 0, stream>>>(red, coords, tv, sum123, cnt);
    k_att123<<<1024, 256, 0, stream>>>(sum123, cnt, fcW, fcB);
    k_point<<<256, 1024, 0, stream>>>(red, tv, sum123, cnt, coords, fcW, fcB, fcsW, fcsB,
                                      fc_W, outW, loW1, loW2, lob2, proj0);

    // reset tv region for atomicMax keys
    hipMemsetAsync(tv, 0, (size_t)TVSEG * CR * sizeof(float), stream);

    k_gather<<<4096, 256, 0, stream>>>(proj0, inv, bxyz, outProj, outLin, (unsigned int*)tv);
    k_fix<<<86400, 256, 0, stream>>>((unsigned int*)tv);
}

// Round 3
// 3062.873 us; speedup vs baseline: 1.4987x; 1.4987x over previous
//
#include <hip/hip_runtime.h>
#include <math.h>

#define NPTS   200000
#define NPAIR  100000
#define CR     64
#define CR2    32

// scale segment counts / offsets
#define NSEG0      1382400
#define CNT_OFF1   1382400
#define CNT_OFF2   1555200
#define CNT_OFF3   1612800
#define CNT_TOTAL  1634400
#define SUM123_ROW2 172800   // s2 row offset inside sum123
#define SUM123_ROW3 230400   // s3 row offset inside sum123
#define SUM123_ROWS 252000   // total rows in sum123 (s1+s2+s3)

#define TVSEG  1382400       // B*GZ2*GY2*GX2 = 2*16*180*240
#define GX2    240
#define GY2    180
#define GZ2    16

__device__ __forceinline__ int lin_scale(int b, int x, int y, int z,
                                         int ps, int dx, int dy, int dz) {
    int qx = x / ps, qy = y / ps, qz = z / ps;
    return ((b * dx + qx) * dy + qy) * dz + qz;
}

// ---------------- K1: reduced = relu(input @ W_red + b_red) ----------------
__global__ __launch_bounds__(256) void k_reduced(
        const float* __restrict__ in, const float* __restrict__ Wred,
        const float* __restrict__ bred, float* __restrict__ red) {
    __shared__ float Wl[CR * CR];
    __shared__ float bl[CR];
    for (int i = threadIdx.x; i < CR * CR; i += blockDim.x) Wl[i] = Wred[i];
    if (threadIdx.x < CR) bl[threadIdx.x] = bred[threadIdx.x];
    __syncthreads();
    int lane = threadIdx.x & 63;
    int wid  = blockIdx.x * (blockDim.x >> 6) + (threadIdx.x >> 6);
    int nw   = gridDim.x * (blockDim.x >> 6);
    for (int r = wid; r < NPTS; r += nw) {
        float x = in[r * CR + lane];
        float acc = bl[lane];
#pragma unroll
        for (int k = 0; k < CR; ++k)
            acc += __shfl(x, k, 64) * Wl[k * CR + lane];
        red[r * CR + lane] = fmaxf(acc, 0.f);
    }
}

// ---------------- K2: scatter-add segment sums + counts ----------------
__global__ __launch_bounds__(256) void k_scatter(
        const float* __restrict__ red, const int* __restrict__ coords,
        float* __restrict__ sum0, float* __restrict__ sum123,
        float* __restrict__ cnt) {
    int lane = threadIdx.x & 63;
    int wid  = blockIdx.x * (blockDim.x >> 6) + (threadIdx.x >> 6);
    int nw   = gridDim.x * (blockDim.x >> 6);
    for (int r = wid; r < NPTS; r += nw) {
        int cb = coords[4 * r + 0], cx = coords[4 * r + 1];
        int cy = coords[4 * r + 2], cz = coords[4 * r + 3];
        int l0 = lin_scale(cb, cx, cy, cz, 2, 240, 180, 16);
        int l1 = lin_scale(cb, cx, cy, cz, 4, 120,  90,  8);
        int l2 = lin_scale(cb, cx, cy, cz, 6,  80,  60,  6);
        int l3 = lin_scale(cb, cx, cy, cz, 8,  60,  45,  4);
        float v = red[r * CR + lane];
        atomicAdd(&sum0[(size_t)l0 * CR + lane], v);
        atomicAdd(&sum123[(size_t)l1 * CR + lane], v);
        atomicAdd(&sum123[(size_t)(SUM123_ROW2 + l2) * CR + lane], v);
        atomicAdd(&sum123[(size_t)(SUM123_ROW3 + l3) * CR + lane], v);
        if (lane < 4) {
            int myLin, myOff;
            if (lane == 0)      { myLin = l0; myOff = 0; }
            else if (lane == 1) { myLin = l1; myOff = CNT_OFF1; }
            else if (lane == 2) { myLin = l2; myOff = CNT_OFF2; }
            else                { myLin = l3; myOff = CNT_OFF3; }
            atomicAdd(&cnt[myOff + myLin], 1.0f);
        }
    }
}

// ---------------- K3a: att for scales 1-3, in place into sum123 rows ----------------
__global__ __launch_bounds__(256) void k_att123(
        float* __restrict__ sum123, const float* __restrict__ cnt,
        const float* __restrict__ fcW, const float* __restrict__ fcB) {
    __shared__ float sw[3 * CR * CR2];   // fcW scales 1..3, 24 KB
    for (int i = threadIdx.x; i < 3 * CR * CR2; i += blockDim.x)
        sw[i] = fcW[CR * CR2 + i];
    __syncthreads();
    int lane = threadIdx.x & 63;
    int d = lane & 31;
    int h = lane >> 5;
    float b1 = fcB[1 * CR2 + d], b2 = fcB[2 * CR2 + d], b3 = fcB[3 * CR2 + d];
    int wid = blockIdx.x * (blockDim.x >> 6) + (threadIdx.x >> 6);
    int nw  = gridDim.x * (blockDim.x >> 6);
    for (int s = wid; s < SUM123_ROWS; s += nw) {
        const float* w; int ci; float bj;
        if (s < SUM123_ROW2)      { w = sw;                ci = CNT_OFF1 + s;                 bj = b1; }
        else if (s < SUM123_ROW3) { w = sw + CR * CR2;     ci = CNT_OFF2 + (s - SUM123_ROW2); bj = b2; }
        else                      { w = sw + 2 * CR * CR2; ci = CNT_OFF3 + (s - SUM123_ROW3); bj = b3; }
        float* row = sum123 + (size_t)s * CR;
        float rc = 1.f / fmaxf(cnt[ci], 1.f);
        float m = row[lane] * rc;
        float p = 0.f;
#pragma unroll
        for (int kk = 0; kk < 32; ++kk)
            p += __shfl(m, 32 * h + kk, 64) * w[(32 * h + kk) * CR2 + d];
        float att = fmaxf(p + __shfl_xor(p, 32, 64) + bj, 0.f);
        if (h == 0) row[d] = att;   // in-place, after read
    }
}

// ---------------- K3a0: att for scale 0, in place into tv/sum0 rows ----------------
// Sequential scan over 1.38M rows; ballot-compacted so only non-empty rows
// (~13.5%) pay the row read + matvec.
__global__ __launch_bounds__(256) void k_att0(
        float* __restrict__ tv, const float* __restrict__ cnt0,
        const float* __restrict__ fcW, const float* __restrict__ fcB) {
    __shared__ float sw[CR * CR2];   // fc_list_W[0], 8 KB
    for (int i = threadIdx.x; i < CR * CR2; i += blockDim.x) sw[i] = fcW[i];
    __syncthreads();
    int lane = threadIdx.x & 63;
    int d = lane & 31;
    int h = lane >> 5;
    float b0 = fcB[d];
    int wid = blockIdx.x * (blockDim.x >> 6) + (threadIdx.x >> 6);
    int nw  = gridDim.x * (blockDim.x >> 6);
    for (int base = wid * 64; base < NSEG0; base += nw * 64) {
        float c = cnt0[base + lane];                    // coalesced batch check
        unsigned long long mask = __ballot(c > 0.f);
        while (mask) {
            int j = __ffsll((long long)mask) - 1;
            mask &= mask - 1;
            float cj = __shfl(c, j, 64);
            float* row = tv + (size_t)(base + j) * CR;
            float m = row[lane] / cj;
            float p = 0.f;
#pragma unroll
            for (int kk = 0; kk < 32; ++kk)
                p += __shfl(m, 32 * h + kk, 64) * sw[(32 * h + kk) * CR2 + d];
            float att = fmaxf(p + __shfl_xor(p, 32, 64) + b0, 0.f);
            if (h == 0) row[d] = att;                   // in-place, after read
        }
    }
}

// ---------------- K3b: fused per-point chain -> proj0 ----------------
// Gathers pre-computed att (all 4 scales); weights in LDS; 2 points/iter.
__global__ __launch_bounds__(512) void k_point(
        const float* __restrict__ red,
        const float* __restrict__ att0, const float* __restrict__ sum123,
        const int* __restrict__ coords,
        const float* __restrict__ fcsB,
        const float* __restrict__ fc_W, const float* __restrict__ fcsW,
        const float* __restrict__ outW,
        const float* __restrict__ loW1, const float* __restrict__ loW2,
        const float* __restrict__ lob2, float* __restrict__ proj0) {
    __shared__ float sw[19456];          // 76 KB
    float* s_fcZ  = sw;                  // 1024: fc_W (32x32)
    float* s_fcs  = sw + 1024;           // 4096: fcsW (4x32x32)
    float* s_out  = sw + 5120;           // 2048: out_fc_W (32x64)
    float* s_W1   = sw + 7168;           // 8192: lo_W1 (128x64)
    float* s_W2   = sw + 15360;          // 4096: lo_W2 (64x64)
    for (int i = threadIdx.x; i < 1024; i += blockDim.x) s_fcZ[i] = fc_W[i];
    for (int i = threadIdx.x; i < 4096; i += blockDim.x) s_fcs[i] = fcsW[i];
    for (int i = threadIdx.x; i < 2048; i += blockDim.x) s_out[i] = outW[i];
    for (int i = threadIdx.x; i < 8192; i += blockDim.x) s_W1[i]  = loW1[i];
    for (int i = threadIdx.x; i < 4096; i += blockDim.x) s_W2[i]  = loW2[i];
    __syncthreads();

    int lane = threadIdx.x & 63;
    int d = lane & 31;
    int h = lane >> 5;
    float vbA = fcsB[(h ? 1 : 0) * CR2 + d];
    float vbB = fcsB[(h ? 3 : 2) * CR2 + d];
    float lob = lob2[lane];
    const float* VA = s_fcs + (h ? 1 : 0) * CR2 * CR2;
    const float* VB = s_fcs + (h ? 3 : 2) * CR2 * CR2;

    int wid = blockIdx.x * (blockDim.x >> 6) + (threadIdx.x >> 6);
    int nw  = gridDim.x * (blockDim.x >> 6);
    for (int pi = wid; pi < NPAIR; pi += nw) {
        int r0 = 2 * pi, r1 = r0 + 1;
        int4 c0 = ((const int4*)coords)[r0];
        int4 c1 = ((const int4*)coords)[r1];
        int l0a = lin_scale(c0.x, c0.y, c0.z, c0.w, 2, 240, 180, 16);
        int l1a = lin_scale(c0.x, c0.y, c0.z, c0.w, 4, 120,  90,  8);
        int l2a = lin_scale(c0.x, c0.y, c0.z, c0.w, 6,  80,  60,  6);
        int l3a = lin_scale(c0.x, c0.y, c0.z, c0.w, 8,  60,  45,  4);
        int l0b = lin_scale(c1.x, c1.y, c1.z, c1.w, 2, 240, 180, 16);
        int l1b = lin_scale(c1.x, c1.y, c1.z, c1.w, 4, 120,  90,  8);
        int l2b = lin_scale(c1.x, c1.y, c1.z, c1.w, 6,  80,  60,  6);
        int l3b = lin_scale(c1.x, c1.y, c1.z, c1.w, 8,  60,  45,  4);

        float xr0 = red[(size_t)r0 * CR + lane];
        float xr1 = red[(size_t)r1 * CR + lane];
        // gather materialized att (all scales), replicated across halves
        float a0_0 = att0[(size_t)l0a * CR + d];
        float a1_0 = sum123[(size_t)l1a * CR + d];
        float a2_0 = sum123[(size_t)(SUM123_ROW2 + l2a) * CR + d];
        float a3_0 = sum123[(size_t)(SUM123_ROW3 + l3a) * CR + d];
        float a0_1 = att0[(size_t)l0b * CR + d];
        float a1_1 = sum123[(size_t)l1b * CR + d];
        float a2_1 = sum123[(size_t)(SUM123_ROW2 + l2b) * CR + d];
        float a3_1 = sum123[(size_t)(SUM123_ROW3 + l3b) * CR + d];

        float fS0 = a0_0 + a1_0 + a2_0 + a3_0;   // replicated across halves
        float fS1 = a0_1 + a1_1 + a2_1 + a3_1;

        // featZ = relu(featS @ fc_W)
        float az0 = 0.f, az1 = 0.f;
#pragma unroll
        for (int c = 0; c < CR2; ++c) {
            float w = s_fcZ[c * CR2 + d];
            az0 += __shfl(fS0, c, 64) * w;
            az1 += __shfl(fS1, c, 64) * w;
        }
        float fZ0 = fmaxf(az0, 0.f), fZ1 = fmaxf(az1, 0.f);

        // att_v (sigmoid); half h handles scales {h, 2+h}
        float avA0 = vbA, avB0 = vbB, avA1 = vbA, avB1 = vbB;
#pragma unroll
        for (int c = 0; c < CR2; ++c) {
            float wa = VA[c * CR2 + d];
            float wb = VB[c * CR2 + d];
            float fz0 = __shfl(fZ0, c, 64);
            float fz1 = __shfl(fZ1, c, 64);
            avA0 += fz0 * wa; avB0 += fz0 * wb;
            avA1 += fz1 * wa; avB1 += fz1 * wb;
        }
        avA0 = 1.f / (1.f + __expf(-avA0));
        avB0 = 1.f / (1.f + __expf(-avB0));
        avA1 = 1.f / (1.f + __expf(-avA1));
        avB1 = 1.f / (1.f + __expf(-avB1));

        float sA0 = h ? a1_0 : a0_0, sB0 = h ? a3_0 : a2_0;
        float sA1 = h ? a1_1 : a0_1, sB1 = h ? a3_1 : a2_1;
        float u0 = sA0 * avA0 + sB0 * avB0;
        float u1 = sA1 * avA1 + sB1 * avB1;
        float fI0 = u0 + __shfl_xor(u0, 32, 64);
        float fI1 = u1 + __shfl_xor(u1, 32, 64);

        // fused = fusedIn @ out_fc_W
        float fu0 = 0.f, fu1 = 0.f;
#pragma unroll
        for (int dd = 0; dd < CR2; ++dd) {
            float w = s_out[dd * CR + lane];
            fu0 += __shfl(fI0, dd, 64) * w;
            fu1 += __shfl(fI1, dd, 64) * w;
        }

        // h = relu([reduced, fused] @ lo_W1)
        float h0 = 0.f, h1 = 0.f;
#pragma unroll
        for (int k = 0; k < CR; ++k) {
            float w = s_W1[k * CR + lane];
            h0 += __shfl(xr0, k, 64) * w;
            h1 += __shfl(xr1, k, 64) * w;
        }
#pragma unroll
        for (int k = 0; k < CR; ++k) {
            float w = s_W1[(CR + k) * CR + lane];
            h0 += __shfl(fu0, k, 64) * w;
            h1 += __shfl(fu1, k, 64) * w;
        }
        h0 = fmaxf(h0, 0.f); h1 = fmaxf(h1, 0.f);

        // proj = h @ lo_W2 + lo_b2
        float q0 = lob, q1 = lob;
#pragma unroll
        for (int k = 0; k < CR; ++k) {
            float w = s_W2[k * CR + lane];
            q0 += __shfl(h0, k, 64) * w;
            q1 += __shfl(h1, k, 64) * w;
        }
        proj0[(size_t)r0 * CR + lane] = q0;
        proj0[(size_t)r1 * CR + lane] = q1;
    }
}

// orderable-uint encoding for float max
__device__ __forceinline__ unsigned int fkey(float f) {
    unsigned int b = __float_as_uint(f);
    return (b & 0x80000000u) ? ~b : (b | 0x80000000u);
}

// ---------------- K4: gather proj, write lin2, scatter tv keys ----------------
__global__ __launch_bounds__(256) void k_gather(
        const float* __restrict__ proj0, const int* __restrict__ inv,
        const int* __restrict__ bxyz, float* __restrict__ outProj,
        float* __restrict__ outLin, unsigned int* __restrict__ tvKey) {
    int lane = threadIdx.x & 63;
    int wid  = blockIdx.x * (blockDim.x >> 6) + (threadIdx.x >> 6);
    int nw   = gridDim.x * (blockDim.x >> 6);
    for (int i = wid; i < NPTS; i += nw) {
        int src = inv[i];
        float v = proj0[(size_t)src * CR + lane];
        outProj[(size_t)i * CR + lane] = v;
        int b = bxyz[4 * i + 0], x = bxyz[4 * i + 1];
        int y = bxyz[4 * i + 2], z = bxyz[4 * i + 3];
        int lin2 = ((b * GZ2 + z) * GY2 + y) * GX2 + x;
        if (lane == 0) outLin[i] = (float)lin2;
        atomicMax(&tvKey[(size_t)lin2 * CR + lane], fkey(v));
    }
}

// ---------------- K5: decode tv keys in place (empty -> 0) ----------------
__global__ __launch_bounds__(256) void k_fix(unsigned int* __restrict__ tv) {
    size_t i = ((size_t)blockIdx.x * blockDim.x + threadIdx.x) * 4;
    if (i >= (size_t)TVSEG * CR) return;
    uint4 k = *(const uint4*)(tv + i);
    float4 f;
    f.x = (k.x == 0u) ? 0.f : __uint_as_float((k.x & 0x80000000u) ? (k.x & 0x7FFFFFFFu) : ~k.x);
    f.y = (k.y == 0u) ? 0.f : __uint_as_float((k.y & 0x80000000u) ? (k.y & 0x7FFFFFFFu) : ~k.y);
    f.z = (k.z == 0u) ? 0.f : __uint_as_float((k.z & 0x80000000u) ? (k.z & 0x7FFFFFFFu) : ~k.z);
    f.w = (k.w == 0u) ? 0.f : __uint_as_float((k.w & 0x80000000u) ? (k.w & 0x7FFFFFFFu) : ~k.w);
    *(float4*)(tv + i) = f;
}

extern "C" void kernel_launch(void* const* d_in, const int* in_sizes, int n_in,
                              void* d_out, int out_size, void* d_ws, size_t ws_size,
                              hipStream_t stream) {
    (void)in_sizes; (void)n_in; (void)out_size; (void)ws_size;
    const float* in_data = (const float*)d_in[0];
    const int*   coords  = (const int*)d_in[1];
    const int*   inv     = (const int*)d_in[2];
    const int*   bxyz    = (const int*)d_in[3];
    const float* W_red   = (const float*)d_in[4];
    const float* b_red   = (const float*)d_in[5];
    const float* fcW     = (const float*)d_in[6];
    const float* fcB     = (const float*)d_in[7];
    const float* fcsW    = (const float*)d_in[8];
    const float* fcsB    = (const float*)d_in[9];
    const float* fc_W    = (const float*)d_in[10];
    const float* outW    = (const float*)d_in[11];
    const float* loW1    = (const float*)d_in[12];
    const float* loW2    = (const float*)d_in[13];
    const float* lob2    = (const float*)d_in[14];

    float* outProj = (float*)d_out;
    float* tv      = outProj + (size_t)NPTS * CR;        // tv region (also sum0/att0 scratch)
    float* outLin  = tv + (size_t)TVSEG * CR;

    float* ws_f   = (float*)d_ws;
    float* red    = ws_f;                                // N*64
    float* sum123 = red + (size_t)NPTS * CR;             // 252000*64 (sums, then att in-place)
    float* cnt    = sum123 + (size_t)SUM123_ROWS * CR;   // 1,634,400
    float* proj0  = cnt + (size_t)CNT_TOTAL;             // N*64

    hipMemsetAsync(tv, 0, (size_t)TVSEG * CR * sizeof(float), stream);
    hipMemsetAsync(sum123, 0, ((size_t)SUM123_ROWS * CR + CNT_TOTAL) * sizeof(float), stream);

    k_reduced<<<2048, 256, 0, stream>>>(in_data, W_red, b_red, red);
    k_scatter<<<4096, 256, 0, stream>>>(red, coords, tv, sum123, cnt);
    k_att123<<<1024, 256, 0, stream>>>(sum123, cnt, fcW, fcB);
    k_att0<<<5400, 256, 0, stream>>>(tv, cnt, fcW, fcB);
    k_point<<<512, 512, 0, stream>>>(red, tv, sum123, coords, fcsB,
                                     fc_W, fcsW, outW, loW1, loW2, lob2, proj0);

    // reset tv region for atomicMax keys
    hipMemsetAsync(tv, 0, (size_t)TVSEG * CR * sizeof(float), stream);

    k_gather<<<4096, 256, 0, stream>>>(proj0, inv, bxyz, outProj, outLin, (unsigned int*)tv);
    k_fix<<<86400, 256, 0, stream>>>((unsigned int*)tv);
}

// Round 4
// 2068.368 us; speedup vs baseline: 2.2193x; 1.4808x over previous
//
#include <hip/hip_runtime.h>
#include <math.h>

#define NPTS   200000
#define NPAIR  100000
#define CR     64
#define CR2    32

// scale segment counts / offsets
#define NSEG0      1382400
#define CNT_OFF1   1382400
#define CNT_OFF2   1555200
#define CNT_OFF3   1612800
#define CNT_TOTAL  1634400
#define SUM123_ROW2 172800   // s2 row offset inside sum123
#define SUM123_ROW3 230400   // s3 row offset inside sum123
#define SUM123_ROWS 252000   // total rows in sum123 (s1+s2+s3)

#define TVSEG  1382400       // B*GZ2*GY2*GX2 = 2*16*180*240
#define GX2    240
#define GY2    180
#define GZ2    16

__device__ __forceinline__ int lin_scale(int b, int x, int y, int z,
                                         int ps, int dx, int dy, int dz) {
    int qx = x / ps, qy = y / ps, qz = z / ps;
    return ((b * dx + qx) * dy + qy) * dz + qz;
}

// ---------------- K1: reduced = relu(input @ W_red + b_red) ----------------
__global__ __launch_bounds__(256) void k_reduced(
        const float* __restrict__ in, const float* __restrict__ Wred,
        const float* __restrict__ bred, float* __restrict__ red) {
    __shared__ float Wl[CR * CR];
    __shared__ float bl[CR];
    for (int i = threadIdx.x; i < CR * CR; i += blockDim.x) Wl[i] = Wred[i];
    if (threadIdx.x < CR) bl[threadIdx.x] = bred[threadIdx.x];
    __syncthreads();
    int lane = threadIdx.x & 63;
    int wid  = blockIdx.x * (blockDim.x >> 6) + (threadIdx.x >> 6);
    int nw   = gridDim.x * (blockDim.x >> 6);
    for (int r = wid; r < NPTS; r += nw) {
        float x = in[r * CR + lane];
        float acc = bl[lane];
#pragma unroll
        for (int k = 0; k < CR; ++k)
            acc += __shfl(x, k, 64) * Wl[k * CR + lane];
        red[r * CR + lane] = fmaxf(acc, 0.f);
    }
}

// ---------------- K2: scatter-add segment sums + counts ----------------
__global__ __launch_bounds__(256) void k_scatter(
        const float* __restrict__ red, const int* __restrict__ coords,
        float* __restrict__ sum0, float* __restrict__ sum123,
        float* __restrict__ cnt) {
    int lane = threadIdx.x & 63;
    int wid  = blockIdx.x * (blockDim.x >> 6) + (threadIdx.x >> 6);
    int nw   = gridDim.x * (blockDim.x >> 6);
    for (int r = wid; r < NPTS; r += nw) {
        int cb = coords[4 * r + 0], cx = coords[4 * r + 1];
        int cy = coords[4 * r + 2], cz = coords[4 * r + 3];
        int l0 = lin_scale(cb, cx, cy, cz, 2, 240, 180, 16);
        int l1 = lin_scale(cb, cx, cy, cz, 4, 120,  90,  8);
        int l2 = lin_scale(cb, cx, cy, cz, 6,  80,  60,  6);
        int l3 = lin_scale(cb, cx, cy, cz, 8,  60,  45,  4);
        float v = red[r * CR + lane];
        atomicAdd(&sum0[(size_t)l0 * CR + lane], v);
        atomicAdd(&sum123[(size_t)l1 * CR + lane], v);
        atomicAdd(&sum123[(size_t)(SUM123_ROW2 + l2) * CR + lane], v);
        atomicAdd(&sum123[(size_t)(SUM123_ROW3 + l3) * CR + lane], v);
        if (lane < 4) {
            int myLin, myOff;
            if (lane == 0)      { myLin = l0; myOff = 0; }
            else if (lane == 1) { myLin = l1; myOff = CNT_OFF1; }
            else if (lane == 2) { myLin = l2; myOff = CNT_OFF2; }
            else                { myLin = l3; myOff = CNT_OFF3; }
            atomicAdd(&cnt[myOff + myLin], 1.0f);
        }
    }
}

// ---------------- K_mm: M = out_fc_W @ lo_W1[64:128]  (32x64) ----------------
__global__ __launch_bounds__(1024) void k_mm(
        const float* __restrict__ outW, const float* __restrict__ loW1,
        float* __restrict__ M) {
    int e = threadIdx.x + blockIdx.x * 1024;   // 2048 elements, grid=2
    if (e >= 2048) return;
    int r = e >> 6, c = e & 63;
    float acc = 0.f;
#pragma unroll
    for (int k = 0; k < 64; ++k)
        acc += outW[r * 64 + k] * loW1[(64 + k) * 64 + c];
    M[e] = acc;
}

// ---------------- K3a: att for scales 1-3, in place into sum123 rows ----------------
__global__ __launch_bounds__(256) void k_att123(
        float* __restrict__ sum123, const float* __restrict__ cnt,
        const float* __restrict__ fcW, const float* __restrict__ fcB) {
    __shared__ float sw[3 * CR * CR2];   // fcW scales 1..3, 24 KB
    for (int i = threadIdx.x; i < 3 * CR * CR2; i += blockDim.x)
        sw[i] = fcW[CR * CR2 + i];
    __syncthreads();
    int lane = threadIdx.x & 63;
    int d = lane & 31;
    int h = lane >> 5;
    float b1 = fcB[1 * CR2 + d], b2 = fcB[2 * CR2 + d], b3 = fcB[3 * CR2 + d];
    int wid = blockIdx.x * (blockDim.x >> 6) + (threadIdx.x >> 6);
    int nw  = gridDim.x * (blockDim.x >> 6);
    for (int s = wid; s < SUM123_ROWS; s += nw) {
        const float* w; int ci; float bj;
        if (s < SUM123_ROW2)      { w = sw;                ci = CNT_OFF1 + s;                 bj = b1; }
        else if (s < SUM123_ROW3) { w = sw + CR * CR2;     ci = CNT_OFF2 + (s - SUM123_ROW2); bj = b2; }
        else                      { w = sw + 2 * CR * CR2; ci = CNT_OFF3 + (s - SUM123_ROW3); bj = b3; }
        float* row = sum123 + (size_t)s * CR;
        float rc = 1.f / fmaxf(cnt[ci], 1.f);
        float m = row[lane] * rc;
        float p = 0.f;
#pragma unroll
        for (int kk = 0; kk < 32; ++kk)
            p += __shfl(m, 32 * h + kk, 64) * w[(32 * h + kk) * CR2 + d];
        float att = fmaxf(p + __shfl_xor(p, 32, 64) + bj, 0.f);
        if (h == 0) row[d] = att;   // in-place, after read
    }
}

// ---------------- K_seg: full per-segment chain -> g, in place in tv rows ----------------
// For each non-empty scale-0 segment: mean -> att0 -> featS (+att1..3 gathered
// with segment-order locality) -> featZ -> att_v -> fusedIn -> g = fI @ M.
// g (64 floats) overwrites the sum0 row.
__global__ __launch_bounds__(256) void k_seg(
        float* __restrict__ tv, const float* __restrict__ sum123,
        const float* __restrict__ cnt,
        const float* __restrict__ fcW, const float* __restrict__ fcB,
        const float* __restrict__ fc_W, const float* __restrict__ fcsW,
        const float* __restrict__ fcsB, const float* __restrict__ M) {
    __shared__ float sw[9216];           // 36 KB
    float* s_fcW0 = sw;                  // 2048: fc_list_W[0] (64x32)
    float* s_fcZ  = sw + 2048;           // 1024: fc_W (32x32)
    float* s_fcs  = sw + 3072;           // 4096: fcsW (4x32x32)
    float* s_M    = sw + 7168;           // 2048: M (32x64)
    for (int i = threadIdx.x; i < 2048; i += blockDim.x) s_fcW0[i] = fcW[i];
    for (int i = threadIdx.x; i < 1024; i += blockDim.x) s_fcZ[i]  = fc_W[i];
    for (int i = threadIdx.x; i < 4096; i += blockDim.x) s_fcs[i]  = fcsW[i];
    for (int i = threadIdx.x; i < 2048; i += blockDim.x) s_M[i]    = M[i];
    __syncthreads();

    int lane = threadIdx.x & 63;
    int d = lane & 31;
    int h = lane >> 5;
    float b0  = fcB[d];
    float vbA = fcsB[(h ? 1 : 0) * CR2 + d];
    float vbB = fcsB[(h ? 3 : 2) * CR2 + d];
    const float* VA = s_fcs + (h ? 1 : 0) * CR2 * CR2;
    const float* VB = s_fcs + (h ? 3 : 2) * CR2 * CR2;

    int wid = blockIdx.x * (blockDim.x >> 6) + (threadIdx.x >> 6);
    int nw  = gridDim.x * (blockDim.x >> 6);
    for (int base = wid * 64; base < NSEG0; base += nw * 64) {
        float c = cnt[base + lane];                 // coalesced batch check
        unsigned long long mask = __ballot(c > 0.f);
        while (mask) {
            int j = __ffsll((long long)mask) - 1;
            mask &= mask - 1;
            int seg = base + j;
            float cj = __shfl(c, j, 64);
            float* row = tv + (size_t)seg * CR;
            float m = row[lane] / cj;

            // decode seg -> coarse-scale rows (wave-uniform scalar math)
            int qz = seg & 15;
            int rest = seg >> 4;
            int qy = rest % 180;
            int rest2 = rest / 180;
            int qx = rest2 % 240;
            int bb = rest2 / 240;
            int l1 = ((bb * 120 + (qx >> 1)) * 90 + (qy >> 1)) * 8 + (qz >> 1);
            int l2 = ((bb *  80 + (qx / 3)) * 60 + (qy / 3)) * 6 + (qz / 3);
            int l3 = ((bb *  60 + (qx >> 2)) * 45 + (qy >> 2)) * 4 + (qz >> 2);
            float a1 = sum123[(size_t)l1 * CR + d];
            float a2 = sum123[(size_t)(SUM123_ROW2 + l2) * CR + d];
            float a3 = sum123[(size_t)(SUM123_ROW3 + l3) * CR + d];

            // att0: half-wave K-split
            float p = 0.f;
#pragma unroll
            for (int kk = 0; kk < 32; ++kk)
                p += __shfl(m, 32 * h + kk, 64) * s_fcW0[(32 * h + kk) * CR2 + d];
            float a0 = fmaxf(p + __shfl_xor(p, 32, 64) + b0, 0.f);

            float fS = a0 + a1 + a2 + a3;           // replicated across halves

            // featZ = relu(featS @ fc_W)
            float az = 0.f;
#pragma unroll
            for (int cc = 0; cc < CR2; ++cc)
                az += __shfl(fS, cc, 64) * s_fcZ[cc * CR2 + d];
            float fZ = fmaxf(az, 0.f);

            // att_v (sigmoid); half h handles scales {h, 2+h}
            float avA = vbA, avB = vbB;
#pragma unroll
            for (int cc = 0; cc < CR2; ++cc) {
                float fz = __shfl(fZ, cc, 64);
                avA += fz * VA[cc * CR2 + d];
                avB += fz * VB[cc * CR2 + d];
            }
            avA = 1.f / (1.f + __expf(-avA));
            avB = 1.f / (1.f + __expf(-avB));

            float sA = h ? a1 : a0, sB = h ? a3 : a2;
            float u = sA * avA + sB * avB;
            float fI = u + __shfl_xor(u, 32, 64);   // fusedIn, replicated

            // g[lane] = fI @ M
            float g = 0.f;
#pragma unroll
            for (int r = 0; r < CR2; ++r)
                g += __shfl(fI, r, 64) * s_M[r * CR + lane];

            row[lane] = g;                          // overwrite sum0 row
        }
    }
}

// ---------------- K3b: per-point tail: proj0 = relu(red@W1a + g[l0]) @ W2 + b ----------------
__global__ __launch_bounds__(256) void k_point(
        const float* __restrict__ red, const float* __restrict__ gtab,
        const int* __restrict__ coords,
        const float* __restrict__ loW1, const float* __restrict__ loW2,
        const float* __restrict__ lob2, float* __restrict__ proj0) {
    __shared__ float sw[8192];           // 32 KB
    float* s_W1 = sw;                    // 4096: lo_W1 rows 0..63
    float* s_W2 = sw + 4096;             // 4096: lo_W2
    for (int i = threadIdx.x; i < 4096; i += blockDim.x) s_W1[i] = loW1[i];
    for (int i = threadIdx.x; i < 4096; i += blockDim.x) s_W2[i] = loW2[i];
    __syncthreads();

    int lane = threadIdx.x & 63;
    float lob = lob2[lane];
    int wid = blockIdx.x * (blockDim.x >> 6) + (threadIdx.x >> 6);
    int nw  = gridDim.x * (blockDim.x >> 6);
    for (int pi = wid; pi < NPAIR; pi += nw) {
        int r0 = 2 * pi, r1 = r0 + 1;
        int4 c0 = ((const int4*)coords)[r0];
        int4 c1 = ((const int4*)coords)[r1];
        int l0a = lin_scale(c0.x, c0.y, c0.z, c0.w, 2, 240, 180, 16);
        int l0b = lin_scale(c1.x, c1.y, c1.z, c1.w, 2, 240, 180, 16);

        float xr0 = red[(size_t)r0 * CR + lane];
        float xr1 = red[(size_t)r1 * CR + lane];
        float h0 = gtab[(size_t)l0a * CR + lane];
        float h1 = gtab[(size_t)l0b * CR + lane];
#pragma unroll
        for (int k = 0; k < CR; ++k) {
            float w = s_W1[k * CR + lane];
            h0 += __shfl(xr0, k, 64) * w;
            h1 += __shfl(xr1, k, 64) * w;
        }
        h0 = fmaxf(h0, 0.f); h1 = fmaxf(h1, 0.f);

        float q0 = lob, q1 = lob;
#pragma unroll
        for (int k = 0; k < CR; ++k) {
            float w = s_W2[k * CR + lane];
            q0 += __shfl(h0, k, 64) * w;
            q1 += __shfl(h1, k, 64) * w;
        }
        proj0[(size_t)r0 * CR + lane] = q0;
        proj0[(size_t)r1 * CR + lane] = q1;
    }
}

// orderable-uint encoding for float max
__device__ __forceinline__ unsigned int fkey(float f) {
    unsigned int b = __float_as_uint(f);
    return (b & 0x80000000u) ? ~b : (b | 0x80000000u);
}

// ---------------- K4: gather proj, write lin2, scatter tv keys ----------------
__global__ __launch_bounds__(256) void k_gather(
        const float* __restrict__ proj0, const int* __restrict__ inv,
        const int* __restrict__ bxyz, float* __restrict__ outProj,
        float* __restrict__ outLin, unsigned int* __restrict__ tvKey) {
    int lane = threadIdx.x & 63;
    int wid  = blockIdx.x * (blockDim.x >> 6) + (threadIdx.x >> 6);
    int nw   = gridDim.x * (blockDim.x >> 6);
    for (int i = wid; i < NPTS; i += nw) {
        int src = inv[i];
        float v = proj0[(size_t)src * CR + lane];
        outProj[(size_t)i * CR + lane] = v;
        int b = bxyz[4 * i + 0], x = bxyz[4 * i + 1];
        int y = bxyz[4 * i + 2], z = bxyz[4 * i + 3];
        int lin2 = ((b * GZ2 + z) * GY2 + y) * GX2 + x;
        if (lane == 0) outLin[i] = (float)lin2;
        atomicMax(&tvKey[(size_t)lin2 * CR + lane], fkey(v));
    }
}

// ---------------- K5: decode tv keys in place (empty -> 0) ----------------
__global__ __launch_bounds__(256) void k_fix(unsigned int* __restrict__ tv) {
    size_t i = ((size_t)blockIdx.x * blockDim.x + threadIdx.x) * 4;
    if (i >= (size_t)TVSEG * CR) return;
    uint4 k = *(const uint4*)(tv + i);
    float4 f;
    f.x = (k.x == 0u) ? 0.f : __uint_as_float((k.x & 0x80000000u) ? (k.x & 0x7FFFFFFFu) : ~k.x);
    f.y = (k.y == 0u) ? 0.f : __uint_as_float((k.y & 0x80000000u) ? (k.y & 0x7FFFFFFFu) : ~k.y);
    f.z = (k.z == 0u) ? 0.f : __uint_as_float((k.z & 0x80000000u) ? (k.z & 0x7FFFFFFFu) : ~k.z);
    f.w = (k.w == 0u) ? 0.f : __uint_as_float((k.w & 0x80000000u) ? (k.w & 0x7FFFFFFFu) : ~k.w);
    *(float4*)(tv + i) = f;
}

extern "C" void kernel_launch(void* const* d_in, const int* in_sizes, int n_in,
                              void* d_out, int out_size, void* d_ws, size_t ws_size,
                              hipStream_t stream) {
    (void)in_sizes; (void)n_in; (void)out_size; (void)ws_size;
    const float* in_data = (const float*)d_in[0];
    const int*   coords  = (const int*)d_in[1];
    const int*   inv     = (const int*)d_in[2];
    const int*   bxyz    = (const int*)d_in[3];
    const float* W_red   = (const float*)d_in[4];
    const float* b_red   = (const float*)d_in[5];
    const float* fcW     = (const float*)d_in[6];
    const float* fcB     = (const float*)d_in[7];
    const float* fcsW    = (const float*)d_in[8];
    const float* fcsB    = (const float*)d_in[9];
    const float* fc_W    = (const float*)d_in[10];
    const float* outW    = (const float*)d_in[11];
    const float* loW1    = (const float*)d_in[12];
    const float* loW2    = (const float*)d_in[13];
    const float* lob2    = (const float*)d_in[14];

    float* outProj = (float*)d_out;
    float* tv      = outProj + (size_t)NPTS * CR;        // tv region (sum0 -> g table -> keys)
    float* outLin  = tv + (size_t)TVSEG * CR;

    float* ws_f   = (float*)d_ws;
    float* red    = ws_f;                                // N*64
    float* sum123 = red + (size_t)NPTS * CR;             // 252000*64 (sums, then att in-place)
    float* cnt    = sum123 + (size_t)SUM123_ROWS * CR;   // 1,634,400
    float* proj0  = cnt + (size_t)CNT_TOTAL;             // N*64
    float* Mmat   = proj0 + (size_t)NPTS * CR;           // 2048

    hipMemsetAsync(tv, 0, (size_t)TVSEG * CR * sizeof(float), stream);
    hipMemsetAsync(sum123, 0, ((size_t)SUM123_ROWS * CR + CNT_TOTAL) * sizeof(float), stream);

    k_mm<<<2, 1024, 0, stream>>>(outW, loW1, Mmat);
    k_reduced<<<2048, 256, 0, stream>>>(in_data, W_red, b_red, red);
    k_scatter<<<4096, 256, 0, stream>>>(red, coords, tv, sum123, cnt);
    k_att123<<<1024, 256, 0, stream>>>(sum123, cnt, fcW, fcB);
    k_seg<<<5400, 256, 0, stream>>>(tv, sum123, cnt, fcW, fcB, fc_W, fcsW, fcsB, Mmat);
    k_point<<<1024, 256, 0, stream>>>(red, tv, coords, loW1, loW2, lob2, proj0);

    // reset tv region for atomicMax keys
    hipMemsetAsync(tv, 0, (size_t)TVSEG * CR * sizeof(float), stream);

    k_gather<<<4096, 256, 0, stream>>>(proj0, inv, bxyz, outProj, outLin, (unsigned int*)tv);
    k_fix<<<86400, 256, 0, stream>>>((unsigned int*)tv);
}

// Round 5
// 1994.792 us; speedup vs baseline: 2.3011x; 1.0369x over previous
//
#include <hip/hip_runtime.h>
#include <math.h>

#define NPTS   200000
#define NPAIR  100000
#define CR     64
#define CR2    32

// scale segment counts / offsets
#define NSEG0      1382400
#define CNT_OFF1   1382400
#define CNT_OFF2   1555200
#define CNT_OFF3   1612800
#define CNT_TOTAL  1634400
#define SUM123_ROW2 172800   // s2 row offset inside sum123
#define SUM123_ROW3 230400   // s3 row offset inside sum123
#define SUM123_ROWS 252000   // total rows in sum123 (s1+s2+s3)

#define TVSEG  1382400       // B*GZ2*GY2*GX2 = 2*16*180*240
#define GX2    240
#define GY2    180
#define GZ2    16

#define NBATCH 21600         // NSEG0 / 64

__device__ __forceinline__ int lin_scale(int b, int x, int y, int z,
                                         int ps, int dx, int dy, int dz) {
    int qx = x / ps, qy = y / ps, qz = z / ps;
    return ((b * dx + qx) * dy + qy) * dz + qz;
}

// ---------------- K1: reduced = relu(input @ W_red + b_red) ----------------
__global__ __launch_bounds__(256) void k_reduced(
        const float* __restrict__ in, const float* __restrict__ Wred,
        const float* __restrict__ bred, float* __restrict__ red) {
    __shared__ float Wl[CR * CR];
    __shared__ float bl[CR];
    for (int i = threadIdx.x; i < CR * CR; i += blockDim.x) Wl[i] = Wred[i];
    if (threadIdx.x < CR) bl[threadIdx.x] = bred[threadIdx.x];
    __syncthreads();
    int lane = threadIdx.x & 63;
    int wid  = blockIdx.x * (blockDim.x >> 6) + (threadIdx.x >> 6);
    int nw   = gridDim.x * (blockDim.x >> 6);
    for (int r = wid; r < NPTS; r += nw) {
        float x = in[r * CR + lane];
        float acc = bl[lane];
#pragma unroll
        for (int k = 0; k < CR; ++k)
            acc += __shfl(x, k, 64) * Wl[k * CR + lane];
        red[r * CR + lane] = fmaxf(acc, 0.f);
    }
}

// ---------------- K2: scatter-add segment sums + counts ----------------
__global__ __launch_bounds__(256) void k_scatter(
        const float* __restrict__ red, const int* __restrict__ coords,
        float* __restrict__ sum0, float* __restrict__ sum123,
        float* __restrict__ cnt) {
    int lane = threadIdx.x & 63;
    int wid  = blockIdx.x * (blockDim.x >> 6) + (threadIdx.x >> 6);
    int nw   = gridDim.x * (blockDim.x >> 6);
    for (int r = wid; r < NPTS; r += nw) {
        int cb = coords[4 * r + 0], cx = coords[4 * r + 1];
        int cy = coords[4 * r + 2], cz = coords[4 * r + 3];
        int l0 = lin_scale(cb, cx, cy, cz, 2, 240, 180, 16);
        int l1 = lin_scale(cb, cx, cy, cz, 4, 120,  90,  8);
        int l2 = lin_scale(cb, cx, cy, cz, 6,  80,  60,  6);
        int l3 = lin_scale(cb, cx, cy, cz, 8,  60,  45,  4);
        float v = red[r * CR + lane];
        atomicAdd(&sum0[(size_t)l0 * CR + lane], v);
        atomicAdd(&sum123[(size_t)l1 * CR + lane], v);
        atomicAdd(&sum123[(size_t)(SUM123_ROW2 + l2) * CR + lane], v);
        atomicAdd(&sum123[(size_t)(SUM123_ROW3 + l3) * CR + lane], v);
        if (lane < 4) {
            int myLin, myOff;
            if (lane == 0)      { myLin = l0; myOff = 0; }
            else if (lane == 1) { myLin = l1; myOff = CNT_OFF1; }
            else if (lane == 2) { myLin = l2; myOff = CNT_OFF2; }
            else                { myLin = l3; myOff = CNT_OFF3; }
            atomicAdd(&cnt[myOff + myLin], 1.0f);
        }
    }
}

// ---------------- K_mm: M = out_fc_W @ lo_W1[64:128]  (32x64) ----------------
__global__ __launch_bounds__(1024) void k_mm(
        const float* __restrict__ outW, const float* __restrict__ loW1,
        float* __restrict__ M) {
    int e = threadIdx.x + blockIdx.x * 1024;   // 2048 elements, grid=2
    if (e >= 2048) return;
    int r = e >> 6, c = e & 63;
    float acc = 0.f;
#pragma unroll
    for (int k = 0; k < 64; ++k)
        acc += outW[r * 64 + k] * loW1[(64 + k) * 64 + c];
    M[e] = acc;
}

// ---------------- K3a: att for scales 1-3, in place into sum123 rows ----------------
__global__ __launch_bounds__(256) void k_att123(
        float* __restrict__ sum123, const float* __restrict__ cnt,
        const float* __restrict__ fcW, const float* __restrict__ fcB) {
    __shared__ float sw[3 * CR * CR2];   // fcW scales 1..3, 24 KB
    for (int i = threadIdx.x; i < 3 * CR * CR2; i += blockDim.x)
        sw[i] = fcW[CR * CR2 + i];
    __syncthreads();
    int lane = threadIdx.x & 63;
    int d = lane & 31;
    int h = lane >> 5;
    float b1 = fcB[1 * CR2 + d], b2 = fcB[2 * CR2 + d], b3 = fcB[3 * CR2 + d];
    int wid = blockIdx.x * (blockDim.x >> 6) + (threadIdx.x >> 6);
    int nw  = gridDim.x * (blockDim.x >> 6);
    for (int s = wid; s < SUM123_ROWS; s += nw) {
        const float* w; int ci; float bj;
        if (s < SUM123_ROW2)      { w = sw;                ci = CNT_OFF1 + s;                 bj = b1; }
        else if (s < SUM123_ROW3) { w = sw + CR * CR2;     ci = CNT_OFF2 + (s - SUM123_ROW2); bj = b2; }
        else                      { w = sw + 2 * CR * CR2; ci = CNT_OFF3 + (s - SUM123_ROW3); bj = b3; }
        float* row = sum123 + (size_t)s * CR;
        float rc = 1.f / fmaxf(cnt[ci], 1.f);
        float m = row[lane] * rc;
        float p = 0.f;
#pragma unroll
        for (int kk = 0; kk < 32; ++kk)
            p += __shfl(m, 32 * h + kk, 64) * w[(32 * h + kk) * CR2 + d];
        float att = fmaxf(p + __shfl_xor(p, 32, 64) + bj, 0.f);
        if (h == 0) row[d] = att;   // in-place, after read
    }
}

// ---------------- K_seg: per-segment chain, 2 segments per wave (half-wave wide) ----------------
// Persistent grid; each wave grid-strides over 64-row batches, pops TWO
// non-empty segments per iteration (one per 32-lane half, lock-step).
// g (64 floats) overwrites the sum0 row.
__global__ __launch_bounds__(256) void k_seg(
        float* __restrict__ tv, const float* __restrict__ sum123,
        const float* __restrict__ cnt,
        const float* __restrict__ fcW, const float* __restrict__ fcB,
        const float* __restrict__ fc_W, const float* __restrict__ fcsW,
        const float* __restrict__ fcsB, const float* __restrict__ M) {
    __shared__ float sw[9216];           // 36 KB
    float* s_fcW0 = sw;                  // 2048: fc_list_W[0] (64x32)
    float* s_fcZ  = sw + 2048;           // 1024: fc_W (32x32)
    float* s_fcs  = sw + 3072;           // 4096: fcsW (4x32x32)
    float* s_M    = sw + 7168;           // 2048: M (32x64)
    for (int i = threadIdx.x; i < 2048; i += blockDim.x) s_fcW0[i] = fcW[i];
    for (int i = threadIdx.x; i < 1024; i += blockDim.x) s_fcZ[i]  = fc_W[i];
    for (int i = threadIdx.x; i < 4096; i += blockDim.x) s_fcs[i]  = fcsW[i];
    for (int i = threadIdx.x; i < 2048; i += blockDim.x) s_M[i]    = M[i];
    __syncthreads();

    int lane = threadIdx.x & 63;
    int d = lane & 31;          // channel within CR2
    int h = lane >> 5;          // which segment of the pair
    float b0  = fcB[d];
    float vb0 = fcsB[0 * CR2 + d], vb1 = fcsB[1 * CR2 + d];
    float vb2 = fcsB[2 * CR2 + d], vb3 = fcsB[3 * CR2 + d];

    int wid = blockIdx.x * (blockDim.x >> 6) + (threadIdx.x >> 6);
    int nw  = gridDim.x * (blockDim.x >> 6);
    for (int batch = wid; batch < NBATCH; batch += nw) {
        int base = batch * 64;
        float c = cnt[base + lane];                 // coalesced batch check
        unsigned long long mask = __ballot(c > 0.f);
        while (mask) {
            int j0 = __ffsll((long long)mask) - 1; mask &= mask - 1;
            bool has2 = (mask != 0);
            int j1 = j0;
            if (has2) { j1 = __ffsll((long long)mask) - 1; mask &= mask - 1; }
            int jm = h ? j1 : j0;                   // per-half segment
            bool valid = (h == 0) || has2;
            int seg = base + jm;
            float cj = __shfl(c, jm, 64);
            float* row = tv + (size_t)seg * CR;
            float2 m2 = ((const float2*)row)[d];    // 256 B per half, coalesced
            float rinv = 1.f / cj;
            m2.x *= rinv; m2.y *= rinv;

            // decode seg -> coarse-scale rows
            int qz = seg & 15;
            int rest = seg >> 4;
            int qy = rest % 180;
            int rest2 = rest / 180;
            int qx = rest2 % 240;
            int bb = rest2 / 240;
            int l1 = ((bb * 120 + (qx >> 1)) * 90 + (qy >> 1)) * 8 + (qz >> 1);
            int l2 = ((bb *  80 + (qx / 3)) * 60 + (qy / 3)) * 6 + (qz / 3);
            int l3 = ((bb *  60 + (qx >> 2)) * 45 + (qy >> 2)) * 4 + (qz >> 2);
            float a1 = sum123[(size_t)l1 * CR + d];
            float a2 = sum123[(size_t)(SUM123_ROW2 + l2) * CR + d];
            float a3 = sum123[(size_t)(SUM123_ROW3 + l3) * CR + d];

            // att0 (full 64-K, 32-wide within half)
            float p = 0.f;
#pragma unroll
            for (int e = 0; e < 32; ++e) {
                float me0 = __shfl(m2.x, e, 32);
                float me1 = __shfl(m2.y, e, 32);
                p += me0 * s_fcW0[(2 * e) * CR2 + d];
                p += me1 * s_fcW0[(2 * e + 1) * CR2 + d];
            }
            float a0 = fmaxf(p + b0, 0.f);

            float fS = a0 + a1 + a2 + a3;

            // featZ = relu(featS @ fc_W)
            float az = 0.f;
#pragma unroll
            for (int cc = 0; cc < CR2; ++cc)
                az += __shfl(fS, cc, 32) * s_fcZ[cc * CR2 + d];
            float fZ = fmaxf(az, 0.f);

            // att_v for all 4 scales (4 independent accumulators)
            float av0 = vb0, av1 = vb1, av2 = vb2, av3 = vb3;
#pragma unroll
            for (int cc = 0; cc < CR2; ++cc) {
                float fz = __shfl(fZ, cc, 32);
                av0 += fz * s_fcs[0 * 1024 + cc * CR2 + d];
                av1 += fz * s_fcs[1 * 1024 + cc * CR2 + d];
                av2 += fz * s_fcs[2 * 1024 + cc * CR2 + d];
                av3 += fz * s_fcs[3 * 1024 + cc * CR2 + d];
            }
            av0 = 1.f / (1.f + __expf(-av0));
            av1 = 1.f / (1.f + __expf(-av1));
            av2 = 1.f / (1.f + __expf(-av2));
            av3 = 1.f / (1.f + __expf(-av3));

            float fI = a0 * av0 + a1 * av1 + a2 * av2 + a3 * av3;

            // g = fI @ M  (64 outputs, 2 per lane)
            float g0 = 0.f, g1 = 0.f;
#pragma unroll
            for (int dd = 0; dd < CR2; ++dd) {
                float f = __shfl(fI, dd, 32);
                g0 += f * s_M[dd * CR + 2 * d];
                g1 += f * s_M[dd * CR + 2 * d + 1];
            }
            if (valid) ((float2*)row)[d] = make_float2(g0, g1);
        }
    }
}

// ---------------- K3b: per-point tail: proj0 = relu(red@W1a + g[l0]) @ W2 + b ----------------
__global__ __launch_bounds__(256) void k_point(
        const float* __restrict__ red, const float* __restrict__ gtab,
        const int* __restrict__ coords,
        const float* __restrict__ loW1, const float* __restrict__ loW2,
        const float* __restrict__ lob2, float* __restrict__ proj0) {
    __shared__ float sw[8192];           // 32 KB
    float* s_W1 = sw;                    // 4096: lo_W1 rows 0..63
    float* s_W2 = sw + 4096;             // 4096: lo_W2
    for (int i = threadIdx.x; i < 4096; i += blockDim.x) s_W1[i] = loW1[i];
    for (int i = threadIdx.x; i < 4096; i += blockDim.x) s_W2[i] = loW2[i];
    __syncthreads();

    int lane = threadIdx.x & 63;
    float lob = lob2[lane];
    int wid = blockIdx.x * (blockDim.x >> 6) + (threadIdx.x >> 6);
    int nw  = gridDim.x * (blockDim.x >> 6);
    for (int pi = wid; pi < NPAIR; pi += nw) {
        int r0 = 2 * pi, r1 = r0 + 1;
        int4 c0 = ((const int4*)coords)[r0];
        int4 c1 = ((const int4*)coords)[r1];
        int l0a = lin_scale(c0.x, c0.y, c0.z, c0.w, 2, 240, 180, 16);
        int l0b = lin_scale(c1.x, c1.y, c1.z, c1.w, 2, 240, 180, 16);

        float xr0 = red[(size_t)r0 * CR + lane];
        float xr1 = red[(size_t)r1 * CR + lane];
        float h0 = gtab[(size_t)l0a * CR + lane];
        float h1 = gtab[(size_t)l0b * CR + lane];
#pragma unroll
        for (int k = 0; k < CR; ++k) {
            float w = s_W1[k * CR + lane];
            h0 += __shfl(xr0, k, 64) * w;
            h1 += __shfl(xr1, k, 64) * w;
        }
        h0 = fmaxf(h0, 0.f); h1 = fmaxf(h1, 0.f);

        float q0 = lob, q1 = lob;
#pragma unroll
        for (int k = 0; k < CR; ++k) {
            float w = s_W2[k * CR + lane];
            q0 += __shfl(h0, k, 64) * w;
            q1 += __shfl(h1, k, 64) * w;
        }
        proj0[(size_t)r0 * CR + lane] = q0;
        proj0[(size_t)r1 * CR + lane] = q1;
    }
}

// orderable-uint encoding for float max
__device__ __forceinline__ unsigned int fkey(float f) {
    unsigned int b = __float_as_uint(f);
    return (b & 0x80000000u) ? ~b : (b | 0x80000000u);
}

// ---------------- K4: gather proj, write lin2, scatter tv keys ----------------
__global__ __launch_bounds__(256) void k_gather(
        const float* __restrict__ proj0, const int* __restrict__ inv,
        const int* __restrict__ bxyz, float* __restrict__ outProj,
        float* __restrict__ outLin, unsigned int* __restrict__ tvKey) {
    int lane = threadIdx.x & 63;
    int wid  = blockIdx.x * (blockDim.x >> 6) + (threadIdx.x >> 6);
    int nw   = gridDim.x * (blockDim.x >> 6);
    for (int i = wid; i < NPTS; i += nw) {
        int src = inv[i];
        float v = proj0[(size_t)src * CR + lane];
        outProj[(size_t)i * CR + lane] = v;
        int b = bxyz[4 * i + 0], x = bxyz[4 * i + 1];
        int y = bxyz[4 * i + 2], z = bxyz[4 * i + 3];
        int lin2 = ((b * GZ2 + z) * GY2 + y) * GX2 + x;
        if (lane == 0) outLin[i] = (float)lin2;
        atomicMax(&tvKey[(size_t)lin2 * CR + lane], fkey(v));
    }
}

// ---------------- K5: decode tv keys in place (empty -> 0) ----------------
__global__ __launch_bounds__(256) void k_fix(unsigned int* __restrict__ tv) {
    size_t i = ((size_t)blockIdx.x * blockDim.x + threadIdx.x) * 4;
    if (i >= (size_t)TVSEG * CR) return;
    uint4 k = *(const uint4*)(tv + i);
    float4 f;
    f.x = (k.x == 0u) ? 0.f : __uint_as_float((k.x & 0x80000000u) ? (k.x & 0x7FFFFFFFu) : ~k.x);
    f.y = (k.y == 0u) ? 0.f : __uint_as_float((k.y & 0x80000000u) ? (k.y & 0x7FFFFFFFu) : ~k.y);
    f.z = (k.z == 0u) ? 0.f : __uint_as_float((k.z & 0x80000000u) ? (k.z & 0x7FFFFFFFu) : ~k.z);
    f.w = (k.w == 0u) ? 0.f : __uint_as_float((k.w & 0x80000000u) ? (k.w & 0x7FFFFFFFu) : ~k.w);
    *(float4*)(tv + i) = f;
}

extern "C" void kernel_launch(void* const* d_in, const int* in_sizes, int n_in,
                              void* d_out, int out_size, void* d_ws, size_t ws_size,
                              hipStream_t stream) {
    (void)in_sizes; (void)n_in; (void)out_size; (void)ws_size;
    const float* in_data = (const float*)d_in[0];
    const int*   coords  = (const int*)d_in[1];
    const int*   inv     = (const int*)d_in[2];
    const int*   bxyz    = (const int*)d_in[3];
    const float* W_red   = (const float*)d_in[4];
    const float* b_red   = (const float*)d_in[5];
    const float* fcW     = (const float*)d_in[6];
    const float* fcB     = (const float*)d_in[7];
    const float* fcsW    = (const float*)d_in[8];
    const float* fcsB    = (const float*)d_in[9];
    const float* fc_W    = (const float*)d_in[10];
    const float* outW    = (const float*)d_in[11];
    const float* loW1    = (const float*)d_in[12];
    const float* loW2    = (const float*)d_in[13];
    const float* lob2    = (const float*)d_in[14];

    float* outProj = (float*)d_out;
    float* tv      = outProj + (size_t)NPTS * CR;        // tv region (sum0 -> g table -> keys)
    float* outLin  = tv + (size_t)TVSEG * CR;

    float* ws_f   = (float*)d_ws;
    float* red    = ws_f;                                // N*64
    float* sum123 = red + (size_t)NPTS * CR;             // 252000*64 (sums, then att in-place)
    float* cnt    = sum123 + (size_t)SUM123_ROWS * CR;   // 1,634,400
    float* proj0  = cnt + (size_t)CNT_TOTAL;             // N*64
    float* Mmat   = proj0 + (size_t)NPTS * CR;           // 2048

    hipMemsetAsync(tv, 0, (size_t)TVSEG * CR * sizeof(float), stream);
    hipMemsetAsync(sum123, 0, ((size_t)SUM123_ROWS * CR + CNT_TOTAL) * sizeof(float), stream);

    k_mm<<<2, 1024, 0, stream>>>(outW, loW1, Mmat);
    k_reduced<<<2048, 256, 0, stream>>>(in_data, W_red, b_red, red);
    k_scatter<<<4096, 256, 0, stream>>>(red, coords, tv, sum123, cnt);
    k_att123<<<1024, 256, 0, stream>>>(sum123, cnt, fcW, fcB);
    k_seg<<<768, 256, 0, stream>>>(tv, sum123, cnt, fcW, fcB, fc_W, fcsW, fcsB, Mmat);
    k_point<<<1024, 256, 0, stream>>>(red, tv, coords, loW1, loW2, lob2, proj0);

    // reset tv region for atomicMax keys
    hipMemsetAsync(tv, 0, (size_t)TVSEG * CR * sizeof(float), stream);

    k_gather<<<4096, 256, 0, stream>>>(proj0, inv, bxyz, outProj, outLin, (unsigned int*)tv);
    k_fix<<<86400, 256, 0, stream>>>((unsigned int*)tv);
}

// Round 6
// 1402.259 us; speedup vs baseline: 3.2735x; 1.4226x over previous
//
#include <hip/hip_runtime.h>
#include <math.h>

#define NPTS   200000
#define CR     64
#define CR2    32

#define NSEG0      1382400
#define CNT_OFF1   1382400
#define CNT_OFF2   1555200
#define CNT_OFF3   1612800
#define CNT_TOTAL  1634400
#define SUM123_ROW2 172800
#define SUM123_ROW3 230400
#define SUM123_ROWS 252000

#define TVSEG  1382400       // B*GZ2*GY2*GX2 = 2*16*180*240
#define GX2    240
#define GY2    180
#define GZ2    16

#define NBATCH 21600         // NSEG0 / 64

// VALU broadcast: readlane -> SGPR, no DS traffic
__device__ __forceinline__ float bcastf(float v, int l) {
    return __int_as_float(__builtin_amdgcn_readlane(__float_as_int(v), l));
}

__device__ __forceinline__ int lin_scale(int b, int x, int y, int z,
                                         int ps, int dx, int dy, int dz) {
    int qx = x / ps, qy = y / ps, qz = z / ps;
    return ((b * dx + qx) * dy + qy) * dz + qz;
}

__device__ __forceinline__ void seg_decode(int seg, int& l1, int& l2, int& l3) {
    int qz = seg & 15; int rest = seg >> 4;
    int qy = rest % 180; int rest2 = rest / 180;
    int qx = rest2 % 240; int bb = rest2 / 240;
    l1 = ((bb * 120 + (qx >> 1)) * 90 + (qy >> 1)) * 8 + (qz >> 1);
    l2 = ((bb *  80 + (qx / 3)) * 60 + (qy / 3)) * 6 + (qz / 3);
    l3 = ((bb *  60 + (qx >> 2)) * 45 + (qy >> 2)) * 4 + (qz >> 2);
}

// ---------------- K1: reduced = relu(input @ W_red + b_red), 2 rows/iter ----------------
__global__ __launch_bounds__(256) void k_reduced(
        const float* __restrict__ in, const float* __restrict__ Wred,
        const float* __restrict__ bred, float* __restrict__ red) {
    __shared__ float Wl[CR * CR];
    for (int i = threadIdx.x; i < CR * CR; i += blockDim.x) Wl[i] = Wred[i];
    __syncthreads();
    int lane = threadIdx.x & 63;
    float bl = bred[lane];
    int wid  = blockIdx.x * 4 + (threadIdx.x >> 6);
    int nw   = gridDim.x * 4;
    for (int p = wid; p < NPTS / 2; p += nw) {
        int r0 = 2 * p, r1 = r0 + 1;
        float x0 = in[(size_t)r0 * CR + lane];
        float x1 = in[(size_t)r1 * CR + lane];
        float acc0 = bl, acc1 = bl;
#pragma unroll
        for (int k = 0; k < CR; ++k) {
            float w = Wl[k * CR + lane];
            acc0 += bcastf(x0, k) * w;
            acc1 += bcastf(x1, k) * w;
        }
        red[(size_t)r0 * CR + lane] = fmaxf(acc0, 0.f);
        red[(size_t)r1 * CR + lane] = fmaxf(acc1, 0.f);
    }
}

// ---------------- K2: scatter-add segment sums + counts ----------------
__global__ __launch_bounds__(256) void k_scatter(
        const float* __restrict__ red, const int* __restrict__ coords,
        float* __restrict__ sum0, float* __restrict__ sum123,
        float* __restrict__ cnt) {
    int lane = threadIdx.x & 63;
    int wid  = blockIdx.x * 4 + (threadIdx.x >> 6);
    int nw   = gridDim.x * 4;
    for (int r = wid; r < NPTS; r += nw) {
        int cb = coords[4 * r + 0], cx = coords[4 * r + 1];
        int cy = coords[4 * r + 2], cz = coords[4 * r + 3];
        int l0 = lin_scale(cb, cx, cy, cz, 2, 240, 180, 16);
        int l1 = lin_scale(cb, cx, cy, cz, 4, 120,  90,  8);
        int l2 = lin_scale(cb, cx, cy, cz, 6,  80,  60,  6);
        int l3 = lin_scale(cb, cx, cy, cz, 8,  60,  45,  4);
        float v = red[(size_t)r * CR + lane];
        atomicAdd(&sum0[(size_t)l0 * CR + lane], v);
        atomicAdd(&sum123[(size_t)l1 * CR + lane], v);
        atomicAdd(&sum123[(size_t)(SUM123_ROW2 + l2) * CR + lane], v);
        atomicAdd(&sum123[(size_t)(SUM123_ROW3 + l3) * CR + lane], v);
        if (lane < 4) {
            int myLin, myOff;
            if (lane == 0)      { myLin = l0; myOff = 0; }
            else if (lane == 1) { myLin = l1; myOff = CNT_OFF1; }
            else if (lane == 2) { myLin = l2; myOff = CNT_OFF2; }
            else                { myLin = l3; myOff = CNT_OFF3; }
            atomicAdd(&cnt[myOff + myLin], 1.0f);
        }
    }
}

// ---------------- K_mm: M = out_fc_W @ lo_W1[64:128]  (32x64) ----------------
__global__ __launch_bounds__(1024) void k_mm(
        const float* __restrict__ outW, const float* __restrict__ loW1,
        float* __restrict__ M) {
    int e = threadIdx.x + blockIdx.x * 1024;
    if (e >= 2048) return;
    int r = e >> 6, c = e & 63;
    float acc = 0.f;
#pragma unroll
    for (int k = 0; k < 64; ++k)
        acc += outW[r * 64 + k] * loW1[(64 + k) * 64 + c];
    M[e] = acc;
}

// ---------------- K3a: att for scales 1-3, 2 rows/iter, readlane broadcasts ----------------
__global__ __launch_bounds__(256) void k_att123(
        float* __restrict__ sum123, const float* __restrict__ cnt,
        const float* __restrict__ fcW, const float* __restrict__ fcB) {
    __shared__ float sw[3 * CR * CR2];   // 24 KB: fcW scales 1..3
    for (int i = threadIdx.x; i < 3 * CR * CR2; i += blockDim.x)
        sw[i] = fcW[CR * CR2 + i];
    __syncthreads();
    int lane = threadIdx.x & 63;
    int d = lane & 31;
    int h = lane >> 5;
    float b1 = fcB[1 * CR2 + d], b2 = fcB[2 * CR2 + d], b3 = fcB[3 * CR2 + d];
    int wid = blockIdx.x * 4 + (threadIdx.x >> 6);
    int nw  = gridDim.x * 4;
    for (int p = wid; p < SUM123_ROWS / 2; p += nw) {
        int s0 = 2 * p, s1 = s0 + 1;         // pairs never straddle scale bounds
        const float* w; int ci; float bj;
        if (s0 < SUM123_ROW2)      { w = sw;        ci = CNT_OFF1 + s0;                 bj = b1; }
        else if (s0 < SUM123_ROW3) { w = sw + 2048; ci = CNT_OFF2 + (s0 - SUM123_ROW2); bj = b2; }
        else                       { w = sw + 4096; ci = CNT_OFF3 + (s0 - SUM123_ROW3); bj = b3; }
        float* row0 = sum123 + (size_t)s0 * CR;
        float* row1 = sum123 + (size_t)s1 * CR;
        float rc0 = 1.f / fmaxf(cnt[ci], 1.f);
        float rc1 = 1.f / fmaxf(cnt[ci + 1], 1.f);
        float m0 = row0[lane] * rc0;
        float m1 = row1[lane] * rc1;
        float p0 = bj, p1 = bj;
#pragma unroll
        for (int k = 0; k < CR; ++k) {
            float wk = w[k * CR2 + d];
            p0 += bcastf(m0, k) * wk;
            p1 += bcastf(m1, k) * wk;
        }
        float a0v = fmaxf(p0, 0.f), a1v = fmaxf(p1, 0.f);
        float* rr = h ? row1 : row0;
        rr[d] = h ? a1v : a0v;               // in-place, after both reads
    }
}

// ---------------- K_seg: per-segment chain, 4 segments/wave-iter, readlane ----------------
__global__ __launch_bounds__(256) void k_seg(
        float* __restrict__ tv, const float* __restrict__ sum123,
        const float* __restrict__ cnt,
        const float* __restrict__ fcW, const float* __restrict__ fcB,
        const float* __restrict__ fc_W, const float* __restrict__ fcsW,
        const float* __restrict__ fcsB, const float* __restrict__ M) {
    __shared__ float s_fcW0[2048];   // fc_list_W[0] (64x32)
    __shared__ float s_fcZ[1024];    // fc_W (32x32)
    __shared__ float s_fcs[4096];    // fcsW (4x32x32)
    __shared__ float s_M[2048];      // M (32x64)
    for (int i = threadIdx.x; i < 2048; i += 256) s_fcW0[i] = fcW[i];
    for (int i = threadIdx.x; i < 1024; i += 256) s_fcZ[i]  = fc_W[i];
    for (int i = threadIdx.x; i < 4096; i += 256) s_fcs[i]  = fcsW[i];
    for (int i = threadIdx.x; i < 2048; i += 256) s_M[i]    = M[i];
    __syncthreads();

    int lane = threadIdx.x & 63;
    int d = lane & 31;
    int h = lane >> 5;
    float b0  = fcB[d];
    float vbA = fcsB[(h ? 1 : 0) * CR2 + d];
    float vbB = fcsB[(h ? 3 : 2) * CR2 + d];
    const float* VA = s_fcs + (h ? 1 : 0) * 1024;
    const float* VB = s_fcs + (h ? 3 : 2) * 1024;

    int wid = blockIdx.x * 4 + (threadIdx.x >> 6);
    int nw  = gridDim.x * 4;
    for (int batch = wid; batch < NBATCH; batch += nw) {
        int base = batch * 64;
        float c = cnt[base + lane];
        unsigned long long mask = __ballot(c > 0.f);
        while (mask) {
            int j0 = __ffsll((long long)mask) - 1; mask &= mask - 1;
            int n = 1, j1 = j0, j2 = j0, j3 = j0;
            if (mask) { j1 = __ffsll((long long)mask) - 1; mask &= mask - 1; n = 2;
              if (mask) { j2 = __ffsll((long long)mask) - 1; mask &= mask - 1; n = 3;
                if (mask) { j3 = __ffsll((long long)mask) - 1; mask &= mask - 1; n = 4; } } }
            int seg0 = base + j0, seg1 = base + j1, seg2 = base + j2, seg3 = base + j3;
            float* row0 = tv + (size_t)seg0 * CR;
            float* row1 = tv + (size_t)seg1 * CR;
            float* row2 = tv + (size_t)seg2 * CR;
            float* row3 = tv + (size_t)seg3 * CR;
            float m0 = row0[lane] * (1.f / bcastf(c, j0));
            float m1 = row1[lane] * (1.f / bcastf(c, j1));
            float m2 = row2[lane] * (1.f / bcastf(c, j2));
            float m3 = row3[lane] * (1.f / bcastf(c, j3));

            int l1_0, l2_0, l3_0, l1_1, l2_1, l3_1;
            int l1_2, l2_2, l3_2, l1_3, l2_3, l3_3;
            seg_decode(seg0, l1_0, l2_0, l3_0);
            seg_decode(seg1, l1_1, l2_1, l3_1);
            seg_decode(seg2, l1_2, l2_2, l3_2);
            seg_decode(seg3, l1_3, l2_3, l3_3);
            float a1_0 = sum123[(size_t)l1_0 * CR + d];
            float a2_0 = sum123[(size_t)(SUM123_ROW2 + l2_0) * CR + d];
            float a3_0 = sum123[(size_t)(SUM123_ROW3 + l3_0) * CR + d];
            float a1_1 = sum123[(size_t)l1_1 * CR + d];
            float a2_1 = sum123[(size_t)(SUM123_ROW2 + l2_1) * CR + d];
            float a3_1 = sum123[(size_t)(SUM123_ROW3 + l3_1) * CR + d];
            float a1_2 = sum123[(size_t)l1_2 * CR + d];
            float a2_2 = sum123[(size_t)(SUM123_ROW2 + l2_2) * CR + d];
            float a3_2 = sum123[(size_t)(SUM123_ROW3 + l3_2) * CR + d];
            float a1_3 = sum123[(size_t)l1_3 * CR + d];
            float a2_3 = sum123[(size_t)(SUM123_ROW2 + l2_3) * CR + d];
            float a3_3 = sum123[(size_t)(SUM123_ROW3 + l3_3) * CR + d];

            // att0: 4 independent chains, weights amortized
            float p0 = b0, p1 = b0, p2 = b0, p3 = b0;
#pragma unroll
            for (int k = 0; k < CR; ++k) {
                float wk = s_fcW0[k * CR2 + d];
                p0 += bcastf(m0, k) * wk;
                p1 += bcastf(m1, k) * wk;
                p2 += bcastf(m2, k) * wk;
                p3 += bcastf(m3, k) * wk;
            }
            float a0_0 = fmaxf(p0, 0.f), a0_1 = fmaxf(p1, 0.f);
            float a0_2 = fmaxf(p2, 0.f), a0_3 = fmaxf(p3, 0.f);

            float fS0 = a0_0 + a1_0 + a2_0 + a3_0;
            float fS1 = a0_1 + a1_1 + a2_1 + a3_1;
            float fS2 = a0_2 + a1_2 + a2_2 + a3_2;
            float fS3 = a0_3 + a1_3 + a2_3 + a3_3;

            // featZ = relu(featS @ fc_W)
            float z0 = 0.f, z1 = 0.f, z2 = 0.f, z3 = 0.f;
#pragma unroll
            for (int cc = 0; cc < CR2; ++cc) {
                float wz = s_fcZ[cc * CR2 + d];
                z0 += bcastf(fS0, cc) * wz;
                z1 += bcastf(fS1, cc) * wz;
                z2 += bcastf(fS2, cc) * wz;
                z3 += bcastf(fS3, cc) * wz;
            }
            float fZ0 = fmaxf(z0, 0.f), fZ1 = fmaxf(z1, 0.f);
            float fZ2 = fmaxf(z2, 0.f), fZ3 = fmaxf(z3, 0.f);

            // att_v, half h handles scales {h, 2+h}
            float avA0 = vbA, avA1 = vbA, avA2 = vbA, avA3 = vbA;
            float avB0 = vbB, avB1 = vbB, avB2 = vbB, avB3 = vbB;
#pragma unroll
            for (int cc = 0; cc < CR2; ++cc) {
                float wa = VA[cc * CR2 + d];
                float wb = VB[cc * CR2 + d];
                float f0 = bcastf(fZ0, cc), f1 = bcastf(fZ1, cc);
                float f2 = bcastf(fZ2, cc), f3 = bcastf(fZ3, cc);
                avA0 += f0 * wa; avB0 += f0 * wb;
                avA1 += f1 * wa; avB1 += f1 * wb;
                avA2 += f2 * wa; avB2 += f2 * wb;
                avA3 += f3 * wa; avB3 += f3 * wb;
            }
            avA0 = 1.f / (1.f + __expf(-avA0)); avB0 = 1.f / (1.f + __expf(-avB0));
            avA1 = 1.f / (1.f + __expf(-avA1)); avB1 = 1.f / (1.f + __expf(-avB1));
            avA2 = 1.f / (1.f + __expf(-avA2)); avB2 = 1.f / (1.f + __expf(-avB2));
            avA3 = 1.f / (1.f + __expf(-avA3)); avB3 = 1.f / (1.f + __expf(-avB3));

            float u0 = (h ? a1_0 : a0_0) * avA0 + (h ? a3_0 : a2_0) * avB0;
            float u1 = (h ? a1_1 : a0_1) * avA1 + (h ? a3_1 : a2_1) * avB1;
            float u2 = (h ? a1_2 : a0_2) * avA2 + (h ? a3_2 : a2_2) * avB2;
            float u3 = (h ? a1_3 : a0_3) * avA3 + (h ? a3_3 : a2_3) * avB3;
            float fI0 = u0 + __shfl_xor(u0, 32, 64);
            float fI1 = u1 + __shfl_xor(u1, 32, 64);
            float fI2 = u2 + __shfl_xor(u2, 32, 64);
            float fI3 = u3 + __shfl_xor(u3, 32, 64);

            // g = fI @ M (full 64-wide output)
            float g0 = 0.f, g1 = 0.f, g2 = 0.f, g3 = 0.f;
#pragma unroll
            for (int dd = 0; dd < CR2; ++dd) {
                float wm = s_M[dd * CR + lane];
                g0 += bcastf(fI0, dd) * wm;
                g1 += bcastf(fI1, dd) * wm;
                g2 += bcastf(fI2, dd) * wm;
                g3 += bcastf(fI3, dd) * wm;
            }
            row0[lane] = g0;
            if (n > 1) row1[lane] = g1;
            if (n > 2) row2[lane] = g2;
            if (n > 3) row3[lane] = g3;
        }
    }
}

// ---------------- K_pg: proj directly to d_out, 4 points/iter ----------------
__global__ __launch_bounds__(256) void k_pg(
        const float* __restrict__ red, const float* __restrict__ gtab,
        const int* __restrict__ coords, const int* __restrict__ inv,
        const float* __restrict__ loW1, const float* __restrict__ loW2,
        const float* __restrict__ lob2, float* __restrict__ outProj) {
    __shared__ float s_W1[4096];
    __shared__ float s_W2[4096];
    for (int i = threadIdx.x; i < 4096; i += 256) s_W1[i] = loW1[i];
    for (int i = threadIdx.x; i < 4096; i += 256) s_W2[i] = loW2[i];
    __syncthreads();

    int lane = threadIdx.x & 63;
    float lob = lob2[lane];
    int wid = blockIdx.x * 4 + (threadIdx.x >> 6);
    int nw  = gridDim.x * 4;
    for (int q = wid; q < NPTS / 4; q += nw) {
        int i0 = 4 * q, i1 = i0 + 1, i2 = i0 + 2, i3 = i0 + 3;
        int s0 = inv[i0], s1 = inv[i1], s2 = inv[i2], s3 = inv[i3];
        int4 c0 = ((const int4*)coords)[s0];
        int4 c1 = ((const int4*)coords)[s1];
        int4 c2 = ((const int4*)coords)[s2];
        int4 c3 = ((const int4*)coords)[s3];
        int l0 = lin_scale(c0.x, c0.y, c0.z, c0.w, 2, 240, 180, 16);
        int l1 = lin_scale(c1.x, c1.y, c1.z, c1.w, 2, 240, 180, 16);
        int l2 = lin_scale(c2.x, c2.y, c2.z, c2.w, 2, 240, 180, 16);
        int l3 = lin_scale(c3.x, c3.y, c3.z, c3.w, 2, 240, 180, 16);

        float x0 = red[(size_t)s0 * CR + lane];
        float x1 = red[(size_t)s1 * CR + lane];
        float x2 = red[(size_t)s2 * CR + lane];
        float x3 = red[(size_t)s3 * CR + lane];
        float h0 = gtab[(size_t)l0 * CR + lane];
        float h1 = gtab[(size_t)l1 * CR + lane];
        float h2 = gtab[(size_t)l2 * CR + lane];
        float h3 = gtab[(size_t)l3 * CR + lane];
#pragma unroll
        for (int k = 0; k < CR; ++k) {
            float w = s_W1[k * CR + lane];
            h0 += bcastf(x0, k) * w;
            h1 += bcastf(x1, k) * w;
            h2 += bcastf(x2, k) * w;
            h3 += bcastf(x3, k) * w;
        }
        h0 = fmaxf(h0, 0.f); h1 = fmaxf(h1, 0.f);
        h2 = fmaxf(h2, 0.f); h3 = fmaxf(h3, 0.f);

        float q0 = lob, q1 = lob, q2 = lob, q3 = lob;
#pragma unroll
        for (int k = 0; k < CR; ++k) {
            float w = s_W2[k * CR + lane];
            q0 += bcastf(h0, k) * w;
            q1 += bcastf(h1, k) * w;
            q2 += bcastf(h2, k) * w;
            q3 += bcastf(h3, k) * w;
        }
        outProj[(size_t)i0 * CR + lane] = q0;
        outProj[(size_t)i1 * CR + lane] = q1;
        outProj[(size_t)i2 * CR + lane] = q2;
        outProj[(size_t)i3 * CR + lane] = q3;
    }
}

// ---------------- K_clear: zero only the non-empty g rows (48 MB vs 354 MB) ----------------
__global__ __launch_bounds__(256) void k_clear(
        float* __restrict__ tv, const float* __restrict__ cnt) {
    int lane = threadIdx.x & 63;
    int wid = blockIdx.x * 4 + (threadIdx.x >> 6);
    int nw  = gridDim.x * 4;
    for (int batch = wid; batch < NBATCH; batch += nw) {
        int base = batch * 64;
        float c = cnt[base + lane];
        unsigned long long mask = __ballot(c > 0.f);
        while (mask) {
            int j = __ffsll((long long)mask) - 1; mask &= mask - 1;
            tv[(size_t)(base + j) * CR + lane] = 0.f;
        }
    }
}

// orderable-uint encoding for float max
__device__ __forceinline__ unsigned int fkey(float f) {
    unsigned int b = __float_as_uint(f);
    return (b & 0x80000000u) ? ~b : (b | 0x80000000u);
}

// ---------------- K_scatmax: lin2 + atomicMax keys from outProj ----------------
__global__ __launch_bounds__(256) void k_scatmax(
        const float* __restrict__ outProj, const int* __restrict__ bxyz,
        float* __restrict__ outLin, unsigned int* __restrict__ tvKey) {
    int lane = threadIdx.x & 63;
    int wid  = blockIdx.x * 4 + (threadIdx.x >> 6);
    int nw   = gridDim.x * 4;
    for (int i = wid; i < NPTS; i += nw) {
        float v = outProj[(size_t)i * CR + lane];
        int b = bxyz[4 * i + 0], x = bxyz[4 * i + 1];
        int y = bxyz[4 * i + 2], z = bxyz[4 * i + 3];
        int lin2 = ((b * GZ2 + z) * GY2 + y) * GX2 + x;
        if (lane == 0) outLin[i] = (float)lin2;
        atomicMax(&tvKey[(size_t)lin2 * CR + lane], fkey(v));
    }
}

// ---------------- K5: decode tv keys in place; skip untouched (zero) rows ----------------
__global__ __launch_bounds__(256) void k_fix(unsigned int* __restrict__ tv) {
    size_t i = ((size_t)blockIdx.x * blockDim.x + threadIdx.x) * 4;
    if (i >= (size_t)TVSEG * CR) return;
    uint4 k = *(const uint4*)(tv + i);
    if (!(k.x | k.y | k.z | k.w)) return;   // untouched row: stays 0
    float4 f;
    f.x = (k.x == 0u) ? 0.f : __uint_as_float((k.x & 0x80000000u) ? (k.x & 0x7FFFFFFFu) : ~k.x);
    f.y = (k.y == 0u) ? 0.f : __uint_as_float((k.y & 0x80000000u) ? (k.y & 0x7FFFFFFFu) : ~k.y);
    f.z = (k.z == 0u) ? 0.f : __uint_as_float((k.z & 0x80000000u) ? (k.z & 0x7FFFFFFFu) : ~k.z);
    f.w = (k.w == 0u) ? 0.f : __uint_as_float((k.w & 0x80000000u) ? (k.w & 0x7FFFFFFFu) : ~k.w);
    *(float4*)(tv + i) = f;
}

extern "C" void kernel_launch(void* const* d_in, const int* in_sizes, int n_in,
                              void* d_out, int out_size, void* d_ws, size_t ws_size,
                              hipStream_t stream) {
    (void)in_sizes; (void)n_in; (void)out_size; (void)ws_size;
    const float* in_data = (const float*)d_in[0];
    const int*   coords  = (const int*)d_in[1];
    const int*   inv     = (const int*)d_in[2];
    const int*   bxyz    = (const int*)d_in[3];
    const float* W_red   = (const float*)d_in[4];
    const float* b_red   = (const float*)d_in[5];
    const float* fcW     = (const float*)d_in[6];
    const float* fcB     = (const float*)d_in[7];
    const float* fcsW    = (const float*)d_in[8];
    const float* fcsB    = (const float*)d_in[9];
    const float* fc_W    = (const float*)d_in[10];
    const float* outW    = (const float*)d_in[11];
    const float* loW1    = (const float*)d_in[12];
    const float* loW2    = (const float*)d_in[13];
    const float* lob2    = (const float*)d_in[14];

    float* outProj = (float*)d_out;
    float* tv      = outProj + (size_t)NPTS * CR;        // tv region (sum0 -> g -> keys -> tv_fmap)
    float* outLin  = tv + (size_t)TVSEG * CR;

    float* ws_f   = (float*)d_ws;
    float* red    = ws_f;                                // N*64
    float* sum123 = red + (size_t)NPTS * CR;             // 252000*64
    float* cnt    = sum123 + (size_t)SUM123_ROWS * CR;   // 1,634,400
    float* Mmat   = cnt + (size_t)CNT_TOTAL;             // 2048

    hipMemsetAsync(tv, 0, (size_t)TVSEG * CR * sizeof(float), stream);
    hipMemsetAsync(sum123, 0, ((size_t)SUM123_ROWS * CR + CNT_TOTAL) * sizeof(float), stream);

    k_mm<<<2, 1024, 0, stream>>>(outW, loW1, Mmat);
    k_reduced<<<1024, 256, 0, stream>>>(in_data, W_red, b_red, red);
    k_scatter<<<4096, 256, 0, stream>>>(red, coords, tv, sum123, cnt);
    k_att123<<<1024, 256, 0, stream>>>(sum123, cnt, fcW, fcB);
    k_seg<<<1024, 256, 0, stream>>>(tv, sum123, cnt, fcW, fcB, fc_W, fcsW, fcsB, Mmat);
    k_pg<<<1024, 256, 0, stream>>>(red, tv, coords, inv, loW1, loW2, lob2, outProj);
    k_clear<<<512, 256, 0, stream>>>(tv, cnt);
    k_scatmax<<<1024, 256, 0, stream>>>(outProj, bxyz, outLin, (unsigned int*)tv);
    k_fix<<<86400, 256, 0, stream>>>((unsigned int*)tv);
}